// Round 8
// baseline (195.382 us; speedup 1.0000x reference)
//
#include <hip/hip_runtime.h>
#include <cstdint>
#include <cstddef>

// Problem constants
#define S_LEN 1024
#define BATCH 2
#define DM    1024
#define NH    16
#define DH    64
#define CC    32     // compressed length
#define SB    2048   // S*B rows
#define TSD   128
#define NCHD  8

using short8 = __attribute__((ext_vector_type(8))) short;
using f32x4  = __attribute__((ext_vector_type(4))) float;

__device__ __forceinline__ float b2f(unsigned short u) {
    union { unsigned int i; float f; } v; v.i = ((unsigned int)u) << 16; return v.f;
}
__device__ __forceinline__ unsigned short f2b(float f) {
    union { float f; unsigned int i; } v; v.f = f;
    unsigned int x = v.i;
    unsigned int r = x + 0x7FFFu + ((x >> 16) & 1u);
    return (unsigned short)(r >> 16);
}

__device__ __forceinline__ void async_ld16(const unsigned short* g, unsigned short* l) {
    __builtin_amdgcn_global_load_lds(
        (const __attribute__((address_space(1))) unsigned int*)g,
        (__attribute__((address_space(3))) unsigned int*)l,
        16, 0, 0);
}

// convert 8 consecutive f32 -> short8 bf16 (same f2b as the old k_convert)
__device__ __forceinline__ short8 cvt8(const float* s) {
    float4 v0 = *(const float4*)s;
    float4 v1 = *(const float4*)(s + 4);
    short8 o;
    o[0] = f2b(v0.x); o[1] = f2b(v0.y); o[2] = f2b(v0.z); o[3] = f2b(v0.w);
    o[4] = f2b(v1.x); o[5] = f2b(v1.y); o[6] = f2b(v1.z); o[7] = f2b(v1.w);
    return o;
}

// per-wave dtype sniff: identical sample set + threshold as old k_convert
__device__ __forceinline__ int sniff_isbf(const unsigned short* xs) {
    const int l = threadIdx.x & 63;
    int local = 0;
    for (int i = l; i < 1024; i += 64) {
        unsigned e = (xs[i * 2] >> 7) & 0xFF;
        if (e >= 90 && e <= 160) local++;
    }
#pragma unroll
    for (int m = 1; m < 64; m <<= 1) local += __shfl_xor(local, m);
    return local >= 640;
}

__device__ __forceinline__ float bias_at(const void* bias, int col, int isbf) {
    return isbf ? b2f(((const unsigned short*)bias)[col]) : ((const float*)bias)[col];
}

// ---------------------------------------------------------------------------
// k_g1conv: stage-1 projections directly from RAW inputs (z=0,1,2:
// q_u, k_d, v_d; 64x128 tiles, 256 blocks/slice). Inline dtype sniff; if
// f32, operands are reg-staged with f2b conversion (bit-identical LDS
// contents to the old convert-then-async path). z=3: Wo conversion + flag.
// ---------------------------------------------------------------------------
struct G1 {
    const void* B;      // weight raw (f32 or bf16 by sniff)
    const void* bias;   // raw bias
    unsigned short* out;
    float scale;
};

__global__ __launch_bounds__(256) void k_g1conv(
    const void* __restrict__ x, G1 g0, G1 g1, G1 g2,
    int* __restrict__ flag_out,
    const void* __restrict__ wo_raw, unsigned short* __restrict__ Wob)
{
    const unsigned short* xs = (const unsigned short*)x;
    const int isbf = sniff_isbf(xs);
    const int t = threadIdx.x;

    if (blockIdx.z == 3) {
        const int id = blockIdx.y * 8 + blockIdx.x;   // 0..255
        if (id == 0 && t == 0) *flag_out = isbf;
        if (!isbf) {
            const float4* s = (const float4*)wo_raw;
            for (int i = id * 256 + t; i < (DM * DM) / 4; i += 256 * 256) {
                float4 v = s[i];
                ushort4 o;
                o.x = f2b(v.x); o.y = f2b(v.y); o.z = f2b(v.z); o.w = f2b(v.w);
                ((ushort4*)Wob)[i] = o;
            }
        }
        return;
    }

    G1 ga = (blockIdx.z == 0) ? g0 : (blockIdx.z == 1) ? g1 : g2;
    const int m0 = blockIdx.y * 64;
    const int n0 = blockIdx.x * 128;
    __shared__ __align__(16) unsigned short As[2][64 * 32];
    __shared__ __align__(16) unsigned short Bs[2][128 * 32];
    const int w = t >> 6, l = t & 63;
    const int wm = w >> 1, wn = w & 1;
    const int lr = l >> 2;
    const int lk = (l & 3) * 8;
    const int ln = l & 15;
    const int lq = l >> 4;

    f32x4 acc[2][4] = {};

    const int row_a  = m0 + w * 16 + lr;
    const int row_b0 = n0 + w * 32 + lr;
    const int row_b1 = row_b0 + 16;

    if (isbf) {
        const unsigned short* Ab  = xs + (size_t)row_a * DM + lk;
        const unsigned short* Bb0 = (const unsigned short*)ga.B + (size_t)row_b0 * DM + lk;
        const unsigned short* Bb1 = (const unsigned short*)ga.B + (size_t)row_b1 * DM + lk;
        for (int kk = 0; kk < DM; kk += 64) {
#pragma unroll
            for (int hh = 0; hh < 2; ++hh) {
                async_ld16(Ab  + kk + hh * 32, &As[hh][w * 512]);
                async_ld16(Bb0 + kk + hh * 32, &Bs[hh][w * 1024]);
                async_ld16(Bb1 + kk + hh * 32, &Bs[hh][w * 1024 + 512]);
            }
            __syncthreads();
#pragma unroll
            for (int hh = 0; hh < 2; ++hh) {
                short8 af[2], bfr[4];
#pragma unroll
                for (int i = 0; i < 2; ++i)
                    af[i] = *(const short8*)&As[hh][(wm * 32 + i * 16 + ln) * 32 + lq * 8];
#pragma unroll
                for (int j = 0; j < 4; ++j)
                    bfr[j] = *(const short8*)&Bs[hh][(wn * 64 + j * 16 + ln) * 32 + lq * 8];
#pragma unroll
                for (int i = 0; i < 2; ++i)
#pragma unroll
                    for (int j = 0; j < 4; ++j)
                        acc[i][j] = __builtin_amdgcn_mfma_f32_16x16x32_bf16(af[i], bfr[j], acc[i][j], 0, 0, 0);
            }
            __syncthreads();
        }
    } else {
        const float* Af  = (const float*)x    + (size_t)row_a  * DM + lk;
        const float* Bf0 = (const float*)ga.B + (size_t)row_b0 * DM + lk;
        const float* Bf1 = (const float*)ga.B + (size_t)row_b1 * DM + lk;
        for (int kk = 0; kk < DM; kk += 64) {
#pragma unroll
            for (int hh = 0; hh < 2; ++hh) {
                *(short8*)&As[hh][w * 512  + l * 8]       = cvt8(Af  + kk + hh * 32);
                *(short8*)&Bs[hh][w * 1024 + l * 8]       = cvt8(Bf0 + kk + hh * 32);
                *(short8*)&Bs[hh][w * 1024 + 512 + l * 8] = cvt8(Bf1 + kk + hh * 32);
            }
            __syncthreads();
#pragma unroll
            for (int hh = 0; hh < 2; ++hh) {
                short8 af[2], bfr[4];
#pragma unroll
                for (int i = 0; i < 2; ++i)
                    af[i] = *(const short8*)&As[hh][(wm * 32 + i * 16 + ln) * 32 + lq * 8];
#pragma unroll
                for (int j = 0; j < 4; ++j)
                    bfr[j] = *(const short8*)&Bs[hh][(wn * 64 + j * 16 + ln) * 32 + lq * 8];
#pragma unroll
                for (int i = 0; i < 2; ++i)
#pragma unroll
                    for (int j = 0; j < 4; ++j)
                        acc[i][j] = __builtin_amdgcn_mfma_f32_16x16x32_bf16(af[i], bfr[j], acc[i][j], 0, 0, 0);
            }
            __syncthreads();
        }
    }

    const float sc = ga.scale;
#pragma unroll
    for (int j = 0; j < 4; ++j) {
        int col = n0 + wn * 64 + j * 16 + ln;
        float bv = bias_at(ga.bias, col, isbf);
#pragma unroll
        for (int i = 0; i < 2; ++i) {
            int row0 = m0 + wm * 32 + i * 16 + lq * 4;
#pragma unroll
            for (int r = 0; r < 4; ++r) {
                float v = (acc[i][j][r] + bv) * sc;
                ga.out[(size_t)(row0 + r) * DM + col] = f2b(v);
            }
        }
    }
}

// ---------------------------------------------------------------------------
// gemm_f64: final projection, 64x64 tiles, BK=64. Grid (16, 32) = 512
// blocks = 2/CU. A = attout (bf16 ws); B = Wob / woraw by flag; bias raw.
// Output dtype follows sniffed input dtype.
// ---------------------------------------------------------------------------
__global__ __launch_bounds__(256) void gemm_f64(
    const unsigned short* __restrict__ A,
    const unsigned short* __restrict__ B0,   // Wob (f32-case, converted)
    const unsigned short* __restrict__ B1,   // woraw (bf16-case)
    const void* __restrict__ bo,
    const int* __restrict__ flag,
    void* __restrict__ out)
{
    const int isbf = *flag;
    const unsigned short* Bp = isbf ? B1 : B0;
    const int m0 = blockIdx.y * 64;
    const int n0 = blockIdx.x * 64;
    __shared__ __align__(16) unsigned short As[2][64 * 32];
    __shared__ __align__(16) unsigned short Bs[2][64 * 32];
    const int t = threadIdx.x;
    const int w = t >> 6, l = t & 63;
    const int wm = w >> 1, wn = w & 1;
    const int lr = l >> 2;
    const int lk = (l & 3) * 8;
    const int ln = l & 15;
    const int lq = l >> 4;

    f32x4 acc[2][2] = {};

    const unsigned short* Ab = A  + (size_t)(m0 + w * 16 + lr) * DM + lk;
    const unsigned short* Bb = Bp + (size_t)(n0 + w * 16 + lr) * DM + lk;

    for (int kk = 0; kk < DM; kk += 64) {
#pragma unroll
        for (int hh = 0; hh < 2; ++hh) {
            async_ld16(Ab + kk + hh * 32, &As[hh][w * 512]);
            async_ld16(Bb + kk + hh * 32, &Bs[hh][w * 512]);
        }
        __syncthreads();
#pragma unroll
        for (int hh = 0; hh < 2; ++hh) {
            short8 af[2], bfr[2];
#pragma unroll
            for (int i = 0; i < 2; ++i)
                af[i] = *(const short8*)&As[hh][(wm * 32 + i * 16 + ln) * 32 + lq * 8];
#pragma unroll
            for (int j = 0; j < 2; ++j)
                bfr[j] = *(const short8*)&Bs[hh][(wn * 32 + j * 16 + ln) * 32 + lq * 8];
#pragma unroll
            for (int i = 0; i < 2; ++i)
#pragma unroll
                for (int j = 0; j < 2; ++j)
                    acc[i][j] = __builtin_amdgcn_mfma_f32_16x16x32_bf16(af[i], bfr[j], acc[i][j], 0, 0, 0);
        }
        __syncthreads();
    }

    const int f32o = !isbf;
#pragma unroll
    for (int j = 0; j < 2; ++j) {
        int col = n0 + wn * 32 + j * 16 + ln;
        float bv = bias_at(bo, col, isbf);
#pragma unroll
        for (int i = 0; i < 2; ++i) {
            int row0 = m0 + wm * 32 + i * 16 + lq * 4;
#pragma unroll
            for (int r = 0; r < 4; ++r) {
                float v = acc[i][j][r] + bv;
                size_t idx = (size_t)(row0 + r) * DM + col;
                if (f32o) ((float*)out)[idx] = v;
                else      ((unsigned short*)out)[idx] = f2b(v);
            }
        }
    }
}

// ---------------------------------------------------------------------------
// k_g2down: z-fused launch, grid (8, 32, 3). z in {0,1}: stage-2 GEMMs
// (v_dk, v_dv) as 64x128 tiles; A = v_d (bf16 ws, async), B = raw Wk/Wv
// (inline-converted when f32). z==2: the 256 k_down blocks (QD staged with
// inline conversion from raw q_down). LDS union 40448 B.
// ---------------------------------------------------------------------------
struct G2 {
    const void* B;      // Wk or Wv raw
    const void* bias;   // bk or bv raw
    unsigned short* out;
};

__global__ __launch_bounds__(256) void k_g2down(
    const unsigned short* __restrict__ vd, G2 g0, G2 g1,
    const int* __restrict__ flag,
    const unsigned short* __restrict__ kd,
    const void* __restrict__ qd_raw,
    float* __restrict__ wbuf,
    float* __restrict__ cmax,
    float* __restrict__ csum)
{
    __shared__ __align__(16) unsigned char SM[40448];
    const int isbf = *flag;
    const int t = threadIdx.x;
    const int w = t >> 6, l = t & 63;
    const int ln = l & 15, lq = l >> 4;

    if (blockIdx.z < 2) {
        // -------- stage-2 GEMM path (64x128 tile) --------
        unsigned short* As = (unsigned short*)SM;              // 2 x 64*32  = 8192 B
        unsigned short* Bs = (unsigned short*)(SM + 8192);     // 2 x 128*32 = 16384 B
        G2 ga = blockIdx.z ? g1 : g0;
        const int m0 = blockIdx.y * 64;
        const int n0 = blockIdx.x * 128;
        const int wm = w >> 1, wn = w & 1;
        const int lr = l >> 2;
        const int lk = (l & 3) * 8;

        f32x4 acc[2][4] = {};

        const int row_b0 = n0 + w * 32 + lr;
        const int row_b1 = row_b0 + 16;
        const unsigned short* Ab = vd + (size_t)(m0 + w * 16 + lr) * DM + lk;

        if (isbf) {
            const unsigned short* Bb0 = (const unsigned short*)ga.B + (size_t)row_b0 * DM + lk;
            const unsigned short* Bb1 = (const unsigned short*)ga.B + (size_t)row_b1 * DM + lk;
            for (int kk = 0; kk < DM; kk += 64) {
#pragma unroll
                for (int hh = 0; hh < 2; ++hh) {
                    async_ld16(Ab  + kk + hh * 32, &As[hh * 2048 + w * 512]);
                    async_ld16(Bb0 + kk + hh * 32, &Bs[hh * 4096 + w * 1024]);
                    async_ld16(Bb1 + kk + hh * 32, &Bs[hh * 4096 + w * 1024 + 512]);
                }
                __syncthreads();
#pragma unroll
                for (int hh = 0; hh < 2; ++hh) {
                    short8 af[2], bfr[4];
#pragma unroll
                    for (int i = 0; i < 2; ++i)
                        af[i] = *(const short8*)&As[hh * 2048 + (wm * 32 + i * 16 + ln) * 32 + lq * 8];
#pragma unroll
                    for (int j = 0; j < 4; ++j)
                        bfr[j] = *(const short8*)&Bs[hh * 4096 + (wn * 64 + j * 16 + ln) * 32 + lq * 8];
#pragma unroll
                    for (int i = 0; i < 2; ++i)
#pragma unroll
                        for (int j = 0; j < 4; ++j)
                            acc[i][j] = __builtin_amdgcn_mfma_f32_16x16x32_bf16(af[i], bfr[j], acc[i][j], 0, 0, 0);
                }
                __syncthreads();
            }
        } else {
            const float* Bf0 = (const float*)ga.B + (size_t)row_b0 * DM + lk;
            const float* Bf1 = (const float*)ga.B + (size_t)row_b1 * DM + lk;
            for (int kk = 0; kk < DM; kk += 64) {
#pragma unroll
                for (int hh = 0; hh < 2; ++hh) {
                    async_ld16(Ab + kk + hh * 32, &As[hh * 2048 + w * 512]);
                    *(short8*)&Bs[hh * 4096 + w * 1024 + l * 8]       = cvt8(Bf0 + kk + hh * 32);
                    *(short8*)&Bs[hh * 4096 + w * 1024 + 512 + l * 8] = cvt8(Bf1 + kk + hh * 32);
                }
                __syncthreads();
#pragma unroll
                for (int hh = 0; hh < 2; ++hh) {
                    short8 af[2], bfr[4];
#pragma unroll
                    for (int i = 0; i < 2; ++i)
                        af[i] = *(const short8*)&As[hh * 2048 + (wm * 32 + i * 16 + ln) * 32 + lq * 8];
#pragma unroll
                    for (int j = 0; j < 4; ++j)
                        bfr[j] = *(const short8*)&Bs[hh * 4096 + (wn * 64 + j * 16 + ln) * 32 + lq * 8];
#pragma unroll
                    for (int i = 0; i < 2; ++i)
#pragma unroll
                        for (int j = 0; j < 4; ++j)
                            acc[i][j] = __builtin_amdgcn_mfma_f32_16x16x32_bf16(af[i], bfr[j], acc[i][j], 0, 0, 0);
                }
                __syncthreads();
            }
        }

#pragma unroll
        for (int j = 0; j < 4; ++j) {
            int col = n0 + wn * 64 + j * 16 + ln;
            float bv = bias_at(ga.bias, col, isbf);
#pragma unroll
            for (int i = 0; i < 2; ++i) {
                int row0 = m0 + wm * 32 + i * 16 + lq * 4;
#pragma unroll
                for (int r = 0; r < 4; ++r) {
                    float v = acc[i][j][r] + bv;
                    ga.out[(size_t)(row0 + r) * DM + col] = f2b(v);
                }
            }
        }
    } else {
        // -------- k_down path --------
        unsigned short* QD = (unsigned short*)SM;              // 32*72*2  = 4608
        unsigned short* KT = (unsigned short*)(SM + 4608);     // 128*72*2 = 18432
        float* SS          = (float*)(SM + 23040);             // 32*132*4 = 16896
        float* cmf         = (float*)(SM + 39936);             // 128

        const int id = blockIdx.y * 8 + blockIdx.x;            // 0..255
        const int bh = id >> 3;
        const int b = bh >> 4, h = bh & 15;
        const int chunk = id & 7;
        const int s0 = chunk * TSD;

        {
            int r = t >> 3, cb = (t & 7) * 8;   // 256 threads cover 32x64
            if (isbf) {
                *(short8*)&QD[r * 72 + cb] =
                    *(const short8*)&((const unsigned short*)qd_raw)[(size_t)r * DM + h * DH + cb];
            } else {
                *(short8*)&QD[r * 72 + cb] =
                    cvt8((const float*)qd_raw + (size_t)r * DM + h * DH + cb);
            }
        }
        for (int u = t; u < 128 * 8; u += 256) {
            int r = u >> 3, cb = (u & 7) * 8;
            *(short8*)&KT[r * 72 + cb] =
                *(const short8*)&kd[(size_t)((s0 + r) * BATCH + b) * DM + h * DH + cb];
        }
        __syncthreads();

        f32x4 accG[2][2] = {};
#pragma unroll
        for (int ks = 0; ks < 2; ++ks) {
            short8 a8[2], b8[2];
#pragma unroll
            for (int i = 0; i < 2; ++i)
                a8[i] = *(const short8*)&QD[(i * 16 + ln) * 72 + ks * 32 + lq * 8];
#pragma unroll
            for (int j = 0; j < 2; ++j)
                b8[j] = *(const short8*)&KT[(w * 32 + j * 16 + ln) * 72 + ks * 32 + lq * 8];
#pragma unroll
            for (int i = 0; i < 2; ++i)
#pragma unroll
                for (int j = 0; j < 2; ++j)
                    accG[i][j] = __builtin_amdgcn_mfma_f32_16x16x32_bf16(a8[i], b8[j], accG[i][j], 0, 0, 0);
        }
#pragma unroll
        for (int i = 0; i < 2; ++i) {
#pragma unroll
            for (int j = 0; j < 2; ++j) {
                int sl = w * 32 + j * 16 + ln;
#pragma unroll
                for (int r = 0; r < 4; ++r) {
                    int c = i * 16 + lq * 4 + r;
                    float v = accG[i][j][r] * 0.125f;
                    SS[c * 132 + sl] = v;
                    wbuf[((size_t)bh * CC + c) * S_LEN + s0 + sl] = v;
                }
            }
        }
        __syncthreads();

        const int c = t >> 3, sub = t & 7;
        float lmax = -3.4e38f;
#pragma unroll
        for (int k = 0; k < 16; ++k) lmax = fmaxf(lmax, SS[c * 132 + sub * 16 + k]);
        lmax = fmaxf(lmax, __shfl_xor(lmax, 1));
        lmax = fmaxf(lmax, __shfl_xor(lmax, 2));
        lmax = fmaxf(lmax, __shfl_xor(lmax, 4));
        if (sub == 0) {
            cmf[c] = lmax;
            cmax[((size_t)bh * CC + c) * NCHD + chunk] = lmax;
        }
        __syncthreads();
        const float cm = cmf[c];
        float es = 0.f;
#pragma unroll
        for (int k = 0; k < 16; ++k) es += __expf(SS[c * 132 + sub * 16 + k] - cm);
        es += __shfl_xor(es, 1);
        es += __shfl_xor(es, 2);
        es += __shfl_xor(es, 4);
        if (sub == 0) csum[((size_t)bh * CC + c) * NCHD + chunk] = es;
    }
}

// ---------------------------------------------------------------------------
// k_wstate: fused k_wapply + k_state. Grid (32 bh, 8 seg).
// ---------------------------------------------------------------------------
__global__ __launch_bounds__(256) void k_wstate(
    const float* __restrict__ wbuf,
    const float* __restrict__ cmax,
    const float* __restrict__ csum,
    const unsigned short* __restrict__ vdk,
    const unsigned short* __restrict__ vdv,
    unsigned short* __restrict__ wb,
    float* __restrict__ invn,
    float* __restrict__ Mst,
    float* __restrict__ NTst)
{
    __shared__ __align__(16) unsigned char SM[45568];
    unsigned short* Wfull = (unsigned short*)SM;             // 32*136*2 = 8704
    unsigned char* R = SM + 8704;                            // 36864-byte reuse region
    // Phase A views
    float* gm    = (float*)R;                                // 128
    float* basep = (float*)(R + 128);                        // 128
    float* psum  = (float*)(R + 256);                        // 32*9*4 = 1152
    float* invt  = (float*)(R + 1408);                       // 128*36*4 = 18432
    // Phase B views
    unsigned short* T1 = (unsigned short*)R;                 // 64*72*2 = 9216
    unsigned short* T2 = (unsigned short*)(R + 9216);        // 9216
    unsigned short* KT = (unsigned short*)(R + 18432);       // 9216
    unsigned short* VT = (unsigned short*)(R + 27648);       // 9216

    const int bh = blockIdx.x, seg = blockIdx.y;
    const int b = bh >> 4, h = bh & 15;
    const int t = threadIdx.x;
    const int w = t >> 6, l = t & 63;
    const int ln = l & 15, lq = l >> 4;

    // ======== Phase A: wapply ========
    if (t < CC) {
        const size_t cb = (size_t)(bh * CC + t) * NCHD;
        float m = cmax[cb];
#pragma unroll
        for (int g = 1; g < NCHD; ++g) m = fmaxf(m, cmax[cb + g]);
        gm[t] = m;
        float bsum = 0.f;
        for (int k = 0; k < seg; ++k)
            bsum += csum[cb + k] * __expf(cmax[cb + k] - m);
        basep[t] = bsum;
    }
    __syncthreads();

    {
        const int c = t >> 3, sub = t & 7;
        const float gmc = gm[c];
        const size_t rbase = (size_t)bh * 32768 + c * 1024 + seg * 128 + sub * 16;
        float w16[16];
        float s = 0.f;
#pragma unroll
        for (int i = 0; i < 16; ++i) {
            float v = __expf(wbuf[rbase + i] - gmc);
            w16[i] = v; s += v;
        }
        psum[c * 9 + sub] = s;
        short8 o0, o1;
#pragma unroll
        for (int i = 0; i < 8; ++i) { o0[i] = f2b(w16[i]); o1[i] = f2b(w16[8 + i]); }
        *(short8*)&wb[rbase] = o0;
        *(short8*)&wb[rbase + 8] = o1;
        *(short8*)&Wfull[c * 136 + sub * 16] = o0;
        *(short8*)&Wfull[c * 136 + sub * 16 + 8] = o1;
        __syncthreads();

        float run = basep[c];
        for (int k = 0; k < sub; ++k) run += psum[c * 9 + k];
#pragma unroll
        for (int i = 0; i < 16; ++i) {
            run += w16[i];
            invt[(sub * 16 + i) * 36 + c] = 1.0f / fmaxf(run, 1e-30f);
        }
    }
    __syncthreads();

    for (int u = t; u < 128 * 8; u += 256) {
        int r = u >> 3, cb2 = (u & 7) * 4;
        *(float4*)&invn[(size_t)bh * 32768 + (seg * 128 + r) * 32 + cb2] =
            *(const float4*)&invt[r * 36 + cb2];
    }
    __syncthreads();   // phase-A LDS reads done before T1/T2 reuse

    // ======== Phase B: state (2 chunks) ========
    for (int rep = 0; rep < 2; ++rep) {
        const int ch = seg * 2 + rep;
        const int s0 = ch * 64;

        for (int u = t; u < 64 * 8; u += 256) {
            int r = u >> 3, cb = (u & 7) * 8;
            *(short8*)&T1[r * 72 + cb] =
                *(const short8*)&vdk[(size_t)((s0 + r) * BATCH + b) * DM + h * DH + cb];
            *(short8*)&T2[r * 72 + cb] =
                *(const short8*)&vdv[(size_t)((s0 + r) * BATCH + b) * DM + h * DH + cb];
        }
        __syncthreads();
        for (int u = t; u < 64 * 8; u += 256) {
            int d = u >> 3, s8 = (u & 7) * 8;
            short8 o1, o2;
#pragma unroll
            for (int k = 0; k < 8; ++k) {
                o1[k] = T1[(s8 + k) * 72 + d];
                o2[k] = T2[(s8 + k) * 72 + d];
            }
            *(short8*)&KT[d * 72 + s8] = o1;
            *(short8*)&VT[d * 72 + s8] = o2;
        }
        __syncthreads();

        f32x4 accM[2] = {};
#pragma unroll
        for (int ks = 0; ks < 2; ++ks) {
            short8 b8 = *(const short8*)&KT[(w * 16 + ln) * 72 + ks * 32 + lq * 8];
#pragma unroll
            for (int i = 0; i < 2; ++i) {
                short8 a8 = *(const short8*)&Wfull[(i * 16 + ln) * 136 + rep * 64 + ks * 32 + lq * 8];
                accM[i] = __builtin_amdgcn_mfma_f32_16x16x32_bf16(a8, b8, accM[i], 0, 0, 0);
            }
        }
#pragma unroll
        for (int i = 0; i < 2; ++i)
#pragma unroll
            for (int r = 0; r < 4; ++r)
                Mst[((size_t)(bh * 16 + ch) * 32 + i * 16 + lq * 4 + r) * 64 + w * 16 + ln] = accM[i][r];

        f32x4 accN[2] = {};
#pragma unroll
        for (int ks = 0; ks < 2; ++ks) {
            short8 a8 = *(const short8*)&VT[(w * 16 + ln) * 72 + ks * 32 + lq * 8];
#pragma unroll
            for (int j = 0; j < 2; ++j) {
                short8 b8 = *(const short8*)&Wfull[(j * 16 + ln) * 136 + rep * 64 + ks * 32 + lq * 8];
                accN[j] = __builtin_amdgcn_mfma_f32_16x16x32_bf16(a8, b8, accN[j], 0, 0, 0);
            }
        }
#pragma unroll
        for (int j = 0; j < 2; ++j)
#pragma unroll
            for (int r = 0; r < 4; ++r)
                NTst[((size_t)(bh * 16 + ch) * 64 + w * 16 + lq * 4 + r) * 32 + j * 16 + ln] = accN[j][r];
        __syncthreads();
    }
}

// ---------------------------------------------------------------------------
// k_att (chunked): per (bh, q-tile 64). Inline exclusive prefix over
// Mst/NTst chunks 0..qi-1; WTd derived by in-LDS transpose of Wd.
// ---------------------------------------------------------------------------
__global__ __launch_bounds__(256) void k_att(
    const unsigned short* __restrict__ qu,
    const unsigned short* __restrict__ vdk,
    const unsigned short* __restrict__ wb,
    const float* __restrict__ invn,
    const unsigned short* __restrict__ vdv,
    const float* __restrict__ Mst,
    const float* __restrict__ NTst,
    unsigned short* __restrict__ attout)
{
    const int bh = blockIdx.x, b = bh >> 4, h = bh & 15;
    const int qi = blockIdx.y;
    const int s0 = qi * 64;
    const int t = threadIdx.x;
    const int w = t >> 6, l = t & 63;
    const int wy = w >> 1, wx = w & 1;
    const int ln = l & 15, lq = l >> 4;

    __shared__ __align__(16) unsigned short Qs[64 * 72];
    __shared__ __align__(16) unsigned short Gs[64 * 72];
    __shared__ __align__(16) unsigned short Kd[64 * 72];
    __shared__ __align__(16) unsigned short Wd[32 * 72];
    __shared__ __align__(16) unsigned short WTd[64 * 40];
    __shared__ __align__(16) unsigned short VTd[64 * 72];
    __shared__ __align__(16) unsigned short Mc[32 * 72];
    __shared__ __align__(16) unsigned short Nc[64 * 40];

    // P0: stage (vdv rows go into Gs temporarily)
    for (int u = t; u < 64 * 8; u += 256) {
        int r = u >> 3, cb = (u & 7) * 8;
        *(short8*)&Qs[r * 72 + cb] =
            *(const short8*)&qu[(size_t)(s0 + r) * 2048 + b * 1024 + h * 64 + cb];
        *(short8*)&Kd[r * 72 + cb] =
            *(const short8*)&vdk[(size_t)(s0 + r) * 2048 + b * 1024 + h * 64 + cb];
        *(short8*)&Gs[r * 72 + cb] =
            *(const short8*)&vdv[(size_t)(s0 + r) * 2048 + b * 1024 + h * 64 + cb];
    }
    for (int u = t; u < 32 * 8; u += 256) {
        int r = u >> 3, cb = (u & 7) * 8;
        *(short8*)&Wd[r * 72 + cb] =
            *(const short8*)&wb[(size_t)bh * 32768 + r * 1024 + s0 + cb];
    }
    // inline exclusive prefix -> Mc (32x64) and Nc (64x32), bf16
    {
        float am[8] = {0.f, 0.f, 0.f, 0.f, 0.f, 0.f, 0.f, 0.f};
        float an[8] = {0.f, 0.f, 0.f, 0.f, 0.f, 0.f, 0.f, 0.f};
        for (int ch = 0; ch < qi; ++ch) {
            const float* pm = Mst + ((size_t)(bh * 16 + ch)) * 2048 + t * 8;
            const float* pn = NTst + ((size_t)(bh * 16 + ch)) * 2048 + t * 8;
            float4 m0 = *(const float4*)pm;
            float4 m1 = *(const float4*)(pm + 4);
            float4 n0 = *(const float4*)pn;
            float4 n1 = *(const float4*)(pn + 4);
            am[0] += m0.x; am[1] += m0.y; am[2] += m0.z; am[3] += m0.w;
            am[4] += m1.x; am[5] += m1.y; am[6] += m1.z; am[7] += m1.w;
            an[0] += n0.x; an[1] += n0.y; an[2] += n0.z; an[3] += n0.w;
            an[4] += n1.x; an[5] += n1.y; an[6] += n1.z; an[7] += n1.w;
        }
        short8 mo, no;
#pragma unroll
        for (int j = 0; j < 8; ++j) { mo[j] = f2b(am[j]); no[j] = f2b(an[j]); }
        *(short8*)&Mc[(t >> 3) * 72 + (t & 7) * 8] = mo;
        *(short8*)&Nc[(t >> 2) * 40 + (t & 3) * 8] = no;
    }
    __syncthreads();

    // P1: VTd[d][s] = Gs[s][d]; WTd[sl][c] = Wd[c][sl]
    for (int u = t; u < 64 * 8; u += 256) {
        int d = u >> 3, s8 = (u & 7) * 8;
        short8 o;
#pragma unroll
        for (int k = 0; k < 8; ++k) o[k] = Gs[(s8 + k) * 72 + d];
        *(short8*)&VTd[d * 72 + s8] = o;
    }
    {
        int sl = t >> 2, cb = (t & 3) * 8;   // 256 units cover 64x32
        short8 o;
#pragma unroll
        for (int k = 0; k < 8; ++k) o[k] = Wd[(cb + k) * 72 + sl];
        *(short8*)&WTd[sl * 40 + cb] = o;
    }
    __syncthreads();

    // P2: G = q @ k_diag^T, causal, -> Gs
    {
        f32x4 accG[2][2] = {};
#pragma unroll
        for (int ks = 0; ks < 2; ++ks) {
            short8 a8[2], b8[2];
#pragma unroll
            for (int i = 0; i < 2; ++i)
                a8[i] = *(const short8*)&Qs[(wy * 32 + i * 16 + ln) * 72 + ks * 32 + lq * 8];
#pragma unroll
            for (int j = 0; j < 2; ++j)
                b8[j] = *(const short8*)&Kd[(wx * 32 + j * 16 + ln) * 72 + ks * 32 + lq * 8];
#pragma unroll
            for (int i = 0; i < 2; ++i)
#pragma unroll
                for (int j = 0; j < 2; ++j)
                    accG[i][j] = __builtin_amdgcn_mfma_f32_16x16x32_bf16(a8[i], b8[j], accG[i][j], 0, 0, 0);
        }
        __syncthreads();  // VTd transpose reads of Gs done before overwrite
#pragma unroll
        for (int i = 0; i < 2; ++i) {
            int row = wy * 32 + i * 16 + lq * 4;
#pragma unroll
            for (int j = 0; j < 2; ++j) {
                int col = wx * 32 + j * 16 + ln;
#pragma unroll
                for (int r = 0; r < 4; ++r) {
                    float v = accG[i][j][r];
                    if (col > row + r) v = 0.f;
                    Gs[(row + r) * 72 + col] = f2b(v);
                }
            }
        }
    }
    __syncthreads();

    // P3: up = G @ w_diag^T + q @ Mcum^T
    f32x4 accU[2] = {};
#pragma unroll
    for (int ks = 0; ks < 2; ++ks) {
        short8 ga = *(const short8*)&Gs[(w * 16 + ln) * 72 + ks * 32 + lq * 8];
        short8 qa = *(const short8*)&Qs[(w * 16 + ln) * 72 + ks * 32 + lq * 8];
#pragma unroll
        for (int j = 0; j < 2; ++j) {
            short8 wf = *(const short8*)&Wd[(j * 16 + ln) * 72 + ks * 32 + lq * 8];
            short8 mf = *(const short8*)&Mc[(j * 16 + ln) * 72 + ks * 32 + lq * 8];
            accU[j] = __builtin_amdgcn_mfma_f32_16x16x32_bf16(ga, wf, accU[j], 0, 0, 0);
            accU[j] = __builtin_amdgcn_mfma_f32_16x16x32_bf16(qa, mf, accU[j], 0, 0, 0);
        }
    }
    __syncthreads();

    // P4: softmax(up*invn) -> ptil into Qs (stride 40)
    {
        int rowl = w * 16 + lq * 4;
#pragma unroll
        for (int r = 0; r < 4; ++r) {
            int srow = s0 + rowl + r;
            float inv0 = invn[(size_t)bh * 32768 + srow * 32 + ln];
            float inv1 = invn[(size_t)bh * 32768 + srow * 32 + 16 + ln];
            float l0 = accU[0][r] * inv0;
            float l1 = accU[1][r] * inv1;
            float m = fmaxf(l0, l1);
#pragma unroll
            for (int msk = 1; msk < 16; msk <<= 1) m = fmaxf(m, __shfl_xor(m, msk));
            float e0 = __expf(l0 - m), e1 = __expf(l1 - m);
            float Z = e0 + e1;
#pragma unroll
            for (int msk = 1; msk < 16; msk <<= 1) Z += __shfl_xor(Z, msk);
            float iz = 1.0f / Z;
            Qs[(rowl + r) * 40 + ln]      = f2b(e0 * iz * inv0);
            Qs[(rowl + r) * 40 + 16 + ln] = f2b(e1 * iz * inv1);
        }
    }
    __syncthreads();

    // P5: SC = ptil @ wT_diag^T (K=32), causal, -> Gs
    short8 pa[2];
#pragma unroll
    for (int i = 0; i < 2; ++i)
        pa[i] = *(const short8*)&Qs[(wy * 32 + i * 16 + ln) * 40 + lq * 8];
    {
        f32x4 accS[2][2] = {};
        short8 b8[2];
#pragma unroll
        for (int j = 0; j < 2; ++j)
            b8[j] = *(const short8*)&WTd[(wx * 32 + j * 16 + ln) * 40 + lq * 8];
#pragma unroll
        for (int i = 0; i < 2; ++i)
#pragma unroll
            for (int j = 0; j < 2; ++j)
                accS[i][j] = __builtin_amdgcn_mfma_f32_16x16x32_bf16(pa[i], b8[j], accS[i][j], 0, 0, 0);
#pragma unroll
        for (int i = 0; i < 2; ++i) {
            int row = wy * 32 + i * 16 + lq * 4;
#pragma unroll
            for (int j = 0; j < 2; ++j) {
                int col = wx * 32 + j * 16 + ln;
#pragma unroll
                for (int r = 0; r < 4; ++r) {
                    float v = accS[i][j][r];
                    if (col > row + r) v = 0.f;
                    Gs[(row + r) * 72 + col] = f2b(v);
                }
            }
        }
    }
    __syncthreads();

    // P6: out = SC @ vT_diag^T + ptil @ NTcum^T -> attout
    {
        f32x4 accO[2][2] = {};
        short8 n8[2];
#pragma unroll
        for (int j = 0; j < 2; ++j)
            n8[j] = *(const short8*)&Nc[(wx * 32 + j * 16 + ln) * 40 + lq * 8];
#pragma unroll
        for (int i = 0; i < 2; ++i)
#pragma unroll
            for (int j = 0; j < 2; ++j)
                accO[i][j] = __builtin_amdgcn_mfma_f32_16x16x32_bf16(pa[i], n8[j], accO[i][j], 0, 0, 0);
#pragma unroll
        for (int ks = 0; ks < 2; ++ks) {
            short8 a8[2], b8[2];
#pragma unroll
            for (int i = 0; i < 2; ++i)
                a8[i] = *(const short8*)&Gs[(wy * 32 + i * 16 + ln) * 72 + ks * 32 + lq * 8];
#pragma unroll
            for (int j = 0; j < 2; ++j)
                b8[j] = *(const short8*)&VTd[(wx * 32 + j * 16 + ln) * 72 + ks * 32 + lq * 8];
#pragma unroll
            for (int i = 0; i < 2; ++i)
#pragma unroll
                for (int j = 0; j < 2; ++j)
                    accO[i][j] = __builtin_amdgcn_mfma_f32_16x16x32_bf16(a8[i], b8[j], accO[i][j], 0, 0, 0);
        }
#pragma unroll
        for (int i = 0; i < 2; ++i) {
            int rowb = s0 + wy * 32 + i * 16 + lq * 4;
#pragma unroll
            for (int j = 0; j < 2; ++j) {
                int d = wx * 32 + j * 16 + ln;
#pragma unroll
                for (int r = 0; r < 4; ++r)
                    attout[(size_t)(rowb + r) * 2048 + b * 1024 + h * 64 + d] = f2b(accO[i][j][r]);
            }
        }
    }
}

// ---------------------------------------------------------------------------
extern "C" void kernel_launch(void* const* d_in, const int* in_sizes, int n_in,
                              void* d_out, int out_size, void* d_ws, size_t ws_size,
                              hipStream_t stream)
{
    (void)in_sizes; (void)n_in; (void)out_size; (void)ws_size;
    char* ws = (char*)d_ws;
    const size_t MB = (size_t)1 << 20;
    const size_t KB = (size_t)1 << 10;
    unsigned short* attout = (unsigned short*)(ws + 0 * MB);   // 4 MB
    unsigned short* q_u    = (unsigned short*)(ws + 4 * MB);   // 4 MB (pre-scaled)
    unsigned short* k_d    = (unsigned short*)(ws + 8 * MB);   // 4 MB
    unsigned short* v_dk   = (unsigned short*)(ws + 12 * MB);  // 4 MB
    unsigned short* v_dv   = (unsigned short*)(ws + 16 * MB);  // 4 MB
    float* wbuf = (float*)(ws + 20 * MB);                      // 4 MB (down scores)
    unsigned short* wb  = (unsigned short*)(ws + 24 * MB);     // 2 MB [bh][c][s]
    float* invn = (float*)(ws + 28 * MB);                      // 4 MB [bh][s][c]
    float* Mst  = (float*)(ws + 32 * MB);                      // 4 MB
    float* NTst = (float*)(ws + 36 * MB);                      // 4 MB
    unsigned short* Wob = (unsigned short*)(ws + 54 * MB);     // 2 MB
    unsigned short* v_d = (unsigned short*)(ws + 56 * MB);     // 4 MB (x@Wv^T+bv)
    float* cmax   = (float*)(ws + 62 * MB + 192 * KB);         // 32 KB
    float* csum   = (float*)(ws + 62 * MB + 256 * KB);         // 32 KB
    int*   flag   = (int*)  (ws + 62 * MB + 320 * KB);

    // stage-1 projections directly from raw inputs (inline sniff + convert):
    // z=0..2 = q_u / k_d / v_d (64x128 tiles, 256 blocks each);
    // z=3 = Wo conversion + flag write. 1024 blocks = 4/CU even.
    G1 gq{ d_in[2], d_in[3], q_u, 0.125f };
    G1 gk{ d_in[4], d_in[5], k_d, 1.0f };
    G1 gv{ d_in[6], d_in[7], v_d, 1.0f };
    k_g1conv<<<dim3(8, 32, 4), 256, 0, stream>>>(d_in[0], gq, gk, gv,
                                                 flag, d_in[8], Wob);

    // fused: stage-2 GEMMs (v_dk, v_dv; z=0,1; 64x128 tiles, raw-W inline
    // convert) + k_down (z=2, raw q_down inline convert). 768 blocks = 3/CU.
    G2 gvk{ d_in[4], d_in[5], v_dk };
    G2 gvv{ d_in[6], d_in[7], v_dv };
    k_g2down<<<dim3(8, 32, 3), 256, 0, stream>>>(v_d, gvk, gvv, flag,
                                                 k_d, d_in[1], wbuf, cmax, csum);

    // fused wapply+state (256 blocks), then att with inline prefix (512 blocks)
    k_wstate<<<dim3(32, 8), 256, 0, stream>>>(wbuf, cmax, csum, v_dk, v_dv,
                                              wb, invn, Mst, NTst);
    k_att<<<dim3(32, 16), 256, 0, stream>>>(q_u, v_dk, wb, invn, v_dv,
                                            Mst, NTst, attout);

    // final projection: 64x64 tiles, 512 blocks = 2/CU
    gemm_f64<<<dim3(16, 32), 256, 0, stream>>>(attout, Wob,
                                               (const unsigned short*)d_in[8],
                                               d_in[9], flag, d_out);
}

// Round 9
// 164.278 us; speedup vs baseline: 1.1893x; 1.1893x over previous
//
#include <hip/hip_runtime.h>
#include <cstdint>
#include <cstddef>

// Problem constants
#define S_LEN 1024
#define BATCH 2
#define DM    1024
#define NH    16
#define DH    64
#define CC    32     // compressed length
#define SB    2048   // S*B rows
#define TSD   128
#define NCHD  8

using short8 = __attribute__((ext_vector_type(8))) short;
using f32x4  = __attribute__((ext_vector_type(4))) float;

__device__ __forceinline__ float b2f(unsigned short u) {
    union { unsigned int i; float f; } v; v.i = ((unsigned int)u) << 16; return v.f;
}
__device__ __forceinline__ unsigned short f2b(float f) {
    union { float f; unsigned int i; } v; v.f = f;
    unsigned int x = v.i;
    unsigned int r = x + 0x7FFFu + ((x >> 16) & 1u);
    return (unsigned short)(r >> 16);
}

__device__ __forceinline__ void async_ld16(const unsigned short* g, unsigned short* l) {
    __builtin_amdgcn_global_load_lds(
        (const __attribute__((address_space(1))) unsigned int*)g,
        (__attribute__((address_space(3))) unsigned int*)l,
        16, 0, 0);
}

// ---------------------------------------------------------------------------
// k_convert: inline dtype sniff. If inputs are bf16, ONLY biases are
// converted (consumers use raw d_in pointers). If fp32, full conversion.
// Wo conversion is deferred to the stage-1 launch (k_g1conv z==3).
// ---------------------------------------------------------------------------
__global__ __launch_bounds__(256) void k_convert(
    const void* x, const void* qd,
    const void* wq, const void* wk, const void* wv,
    const void* bq, const void* bk, const void* bv, const void* bo,
    int* __restrict__ flag,
    unsigned short* xb, unsigned short* qdb,
    unsigned short* Wqb, unsigned short* Wkb, unsigned short* Wvb,
    float* biasf)
{
    __shared__ int cnt;
    if (threadIdx.x == 0) cnt = 0;
    __syncthreads();
    {
        const unsigned short* xs = (const unsigned short*)x;
        int local = 0;
        for (int i = threadIdx.x; i < 1024; i += 256) {
            unsigned e = (xs[i * 2] >> 7) & 0xFF;
            if (e >= 90 && e <= 160) local++;
        }
        atomicAdd(&cnt, local);
    }
    __syncthreads();
    const int isbf = (cnt >= 640);
    if (blockIdx.x == 0 && threadIdx.x == 0) *flag = isbf;

    const size_t tid = (size_t)blockIdx.x * 256 + threadIdx.x;
    const size_t stride = (size_t)gridDim.x * 256;

    if (!isbf) {
        auto cv = [&](const void* src, unsigned short* dst, size_t n) {
            const float4* s = (const float4*)src;
            for (size_t i = tid; i < n / 4; i += stride) {
                float4 v = s[i];
                ushort4 o;
                o.x = f2b(v.x); o.y = f2b(v.y); o.z = f2b(v.z); o.w = f2b(v.w);
                ((ushort4*)dst)[i] = o;
            }
        };
        cv(x,  xb,  (size_t)SB * DM);
        cv(qd, qdb, (size_t)CC * DM);
        cv(wq, Wqb, (size_t)DM * DM);
        cv(wk, Wkb, (size_t)DM * DM);
        cv(wv, Wvb, (size_t)DM * DM);
    }
    for (size_t i = tid; i < 5 * DM; i += stride) {
        int w = (int)(i >> 10), o = (int)(i & 1023);
        float val;
        if (w == 4) val = 0.f;
        else {
            const void* bp = (w == 0) ? bq : ((w == 1) ? bk : ((w == 2) ? bv : bo));
            val = isbf ? b2f(((const unsigned short*)bp)[o]) : ((const float*)bp)[o];
        }
        biasf[i] = val;
    }
}

// ---------------------------------------------------------------------------
// GEMM args. 64-wide-M tile kernels: BK=64.
// ---------------------------------------------------------------------------
struct GArg {
    const unsigned short* A0;
    const unsigned short* A1;
    const unsigned short* B0;
    const unsigned short* B1;
    const float* bias;
    void* out;
    float scale;
    int mode;
};

// ---------------------------------------------------------------------------
// k_g1conv: stage-1 projections (z=0,1,2: q_u, k_d, v_d; 64x128 tiles,
// grid 8x32 per slice = 256 blocks) + deferred Wo conversion (z=3).
// ---------------------------------------------------------------------------
__global__ __launch_bounds__(256) void k_g1conv(
    GArg g0, GArg g1, GArg g2, const int* __restrict__ flag,
    int M, int N, int K,
    const void* __restrict__ wo_raw, unsigned short* __restrict__ Wob)
{
    const int isbf = *flag;
    const int t = threadIdx.x;

    if (blockIdx.z == 3) {
        if (!isbf) {
            const float4* s = (const float4*)wo_raw;
            const int id = blockIdx.y * 8 + blockIdx.x;   // 0..255
            for (int i = id * 256 + t; i < (DM * DM) / 4; i += 256 * 256) {
                float4 v = s[i];
                ushort4 o;
                o.x = f2b(v.x); o.y = f2b(v.y); o.z = f2b(v.z); o.w = f2b(v.w);
                ((ushort4*)Wob)[i] = o;
            }
        }
        return;
    }

    GArg ga = (blockIdx.z == 0) ? g0 : (blockIdx.z == 1) ? g1 : g2;
    const unsigned short* Ap = isbf ? ga.A1 : ga.A0;
    const unsigned short* Bp = isbf ? ga.B1 : ga.B0;
    const int m0 = blockIdx.y * 64;
    const int n0 = blockIdx.x * 128;
    __shared__ __align__(16) unsigned short As[2][64 * 32];
    __shared__ __align__(16) unsigned short Bs[2][128 * 32];
    const int w = t >> 6, l = t & 63;
    const int wm = w >> 1, wn = w & 1;
    const int lr = l >> 2;
    const int lk = (l & 3) * 8;
    const int ln = l & 15;
    const int lq = l >> 4;

    f32x4 acc[2][4] = {};

    const unsigned short* Ab  = Ap + (size_t)(m0 + w * 16 +      lr) * K + lk;
    const unsigned short* Bb0 = Bp + (size_t)(n0 + w * 32 +      lr) * K + lk;
    const unsigned short* Bb1 = Bp + (size_t)(n0 + w * 32 + 16 + lr) * K + lk;

    for (int kk = 0; kk < K; kk += 64) {
#pragma unroll
        for (int hh = 0; hh < 2; ++hh) {
            async_ld16(Ab  + kk + hh * 32, &As[hh][w * 512]);
            async_ld16(Bb0 + kk + hh * 32, &Bs[hh][w * 1024]);
            async_ld16(Bb1 + kk + hh * 32, &Bs[hh][w * 1024 + 512]);
        }
        __syncthreads();
#pragma unroll
        for (int hh = 0; hh < 2; ++hh) {
            short8 af[2], bfr[4];
#pragma unroll
            for (int i = 0; i < 2; ++i)
                af[i] = *(const short8*)&As[hh][(wm * 32 + i * 16 + ln) * 32 + lq * 8];
#pragma unroll
            for (int j = 0; j < 4; ++j)
                bfr[j] = *(const short8*)&Bs[hh][(wn * 64 + j * 16 + ln) * 32 + lq * 8];
#pragma unroll
            for (int i = 0; i < 2; ++i)
#pragma unroll
                for (int j = 0; j < 4; ++j)
                    acc[i][j] = __builtin_amdgcn_mfma_f32_16x16x32_bf16(af[i], bfr[j], acc[i][j], 0, 0, 0);
        }
        __syncthreads();
    }

    const float sc = ga.scale;
#pragma unroll
    for (int j = 0; j < 4; ++j) {
        int col = n0 + wn * 64 + j * 16 + ln;
        float bv = ga.bias[col];
#pragma unroll
        for (int i = 0; i < 2; ++i) {
            int row0 = m0 + wm * 32 + i * 16 + lq * 4;
#pragma unroll
            for (int r = 0; r < 4; ++r) {
                float v = (acc[i][j][r] + bv) * sc;
                ((unsigned short*)ga.out)[(size_t)(row0 + r) * N + col] = f2b(v);
            }
        }
    }
}

// ---------------------------------------------------------------------------
// gemm_f64: final projection, 64x64 tiles, BK=64. Grid (16, 32) = 512
// blocks = 2/CU. mode-2 output (f32 or bf16 by flag).
// ---------------------------------------------------------------------------
__global__ __launch_bounds__(256) void gemm_f64(GArg ga,
                                                const int* __restrict__ flag,
                                                int M, int N, int K)
{
    const int isbf = *flag;
    const unsigned short* Ap = isbf ? ga.A1 : ga.A0;
    const unsigned short* Bp = isbf ? ga.B1 : ga.B0;
    const int m0 = blockIdx.y * 64;
    const int n0 = blockIdx.x * 64;
    __shared__ __align__(16) unsigned short As[2][64 * 32];
    __shared__ __align__(16) unsigned short Bs[2][64 * 32];
    const int t = threadIdx.x;
    const int w = t >> 6, l = t & 63;
    const int wm = w >> 1, wn = w & 1;
    const int lr = l >> 2;
    const int lk = (l & 3) * 8;
    const int ln = l & 15;
    const int lq = l >> 4;

    f32x4 acc[2][2] = {};

    const unsigned short* Ab = Ap + (size_t)(m0 + w * 16 + lr) * K + lk;
    const unsigned short* Bb = Bp + (size_t)(n0 + w * 16 + lr) * K + lk;

    for (int kk = 0; kk < K; kk += 64) {
#pragma unroll
        for (int hh = 0; hh < 2; ++hh) {
            async_ld16(Ab + kk + hh * 32, &As[hh][w * 512]);
            async_ld16(Bb + kk + hh * 32, &Bs[hh][w * 512]);
        }
        __syncthreads();
#pragma unroll
        for (int hh = 0; hh < 2; ++hh) {
            short8 af[2], bfr[2];
#pragma unroll
            for (int i = 0; i < 2; ++i)
                af[i] = *(const short8*)&As[hh][(wm * 32 + i * 16 + ln) * 32 + lq * 8];
#pragma unroll
            for (int j = 0; j < 2; ++j)
                bfr[j] = *(const short8*)&Bs[hh][(wn * 32 + j * 16 + ln) * 32 + lq * 8];
#pragma unroll
            for (int i = 0; i < 2; ++i)
#pragma unroll
                for (int j = 0; j < 2; ++j)
                    acc[i][j] = __builtin_amdgcn_mfma_f32_16x16x32_bf16(af[i], bfr[j], acc[i][j], 0, 0, 0);
        }
        __syncthreads();
    }

    const int f32o = (ga.mode == 0) ? 1 : (ga.mode == 1) ? 0 : (!isbf);
    const float sc = ga.scale;
#pragma unroll
    for (int j = 0; j < 2; ++j) {
        int col = n0 + wn * 32 + j * 16 + ln;
        float bv = ga.bias[col];
#pragma unroll
        for (int i = 0; i < 2; ++i) {
            int row0 = m0 + wm * 32 + i * 16 + lq * 4;
#pragma unroll
            for (int r = 0; r < 4; ++r) {
                float v = (acc[i][j][r] + bv) * sc;
                size_t idx = (size_t)(row0 + r) * N + col;
                if (f32o) ((float*)ga.out)[idx] = v;
                else      ((unsigned short*)ga.out)[idx] = f2b(v);
            }
        }
    }
}

// ---------------------------------------------------------------------------
// k_g2down: z-fused launch, grid (8, 32, 3). z in {0,1}: stage-2 GEMMs
// (v_dk, v_dv) as 64x128 tiles (256 blocks each). z==2: the 256 k_down
// blocks (id = by*8+bx). LDS union: 40448 >= max(gemm 24576, down 40064).
// ---------------------------------------------------------------------------
__global__ __launch_bounds__(256) void k_g2down(
    GArg g0, GArg g1, const int* __restrict__ flag, int M, int N, int K,
    const unsigned short* __restrict__ kd,
    const unsigned short* __restrict__ qd0,
    const unsigned short* __restrict__ qd1,
    float* __restrict__ wbuf,
    float* __restrict__ cmax,
    float* __restrict__ csum)
{
    __shared__ __align__(16) unsigned char SM[40448];
    const int isbf = *flag;
    const int t = threadIdx.x;
    const int w = t >> 6, l = t & 63;
    const int ln = l & 15, lq = l >> 4;

    if (blockIdx.z < 2) {
        // -------- stage-2 GEMM path (64x128 tile) --------
        unsigned short* As = (unsigned short*)SM;              // 2 x 64*32  = 8192 B
        unsigned short* Bs = (unsigned short*)(SM + 8192);     // 2 x 128*32 = 16384 B
        GArg ga = blockIdx.z ? g1 : g0;
        const unsigned short* Ap = isbf ? ga.A1 : ga.A0;
        const unsigned short* Bp = isbf ? ga.B1 : ga.B0;
        const int m0 = blockIdx.y * 64;
        const int n0 = blockIdx.x * 128;
        const int wm = w >> 1, wn = w & 1;
        const int lr = l >> 2;
        const int lk = (l & 3) * 8;

        f32x4 acc[2][4] = {};

        const unsigned short* Ab  = Ap + (size_t)(m0 + w * 16 +      lr) * K + lk;
        const unsigned short* Bb0 = Bp + (size_t)(n0 + w * 32 +      lr) * K + lk;
        const unsigned short* Bb1 = Bp + (size_t)(n0 + w * 32 + 16 + lr) * K + lk;

        for (int kk = 0; kk < K; kk += 64) {
#pragma unroll
            for (int hh = 0; hh < 2; ++hh) {
                async_ld16(Ab  + kk + hh * 32, &As[hh * 2048 + w * 512]);
                async_ld16(Bb0 + kk + hh * 32, &Bs[hh * 4096 + w * 1024]);
                async_ld16(Bb1 + kk + hh * 32, &Bs[hh * 4096 + w * 1024 + 512]);
            }
            __syncthreads();
#pragma unroll
            for (int hh = 0; hh < 2; ++hh) {
                short8 af[2], bfr[4];
#pragma unroll
                for (int i = 0; i < 2; ++i)
                    af[i] = *(const short8*)&As[hh * 2048 + (wm * 32 + i * 16 + ln) * 32 + lq * 8];
#pragma unroll
                for (int j = 0; j < 4; ++j)
                    bfr[j] = *(const short8*)&Bs[hh * 4096 + (wn * 64 + j * 16 + ln) * 32 + lq * 8];
#pragma unroll
                for (int i = 0; i < 2; ++i)
#pragma unroll
                    for (int j = 0; j < 4; ++j)
                        acc[i][j] = __builtin_amdgcn_mfma_f32_16x16x32_bf16(af[i], bfr[j], acc[i][j], 0, 0, 0);
            }
            __syncthreads();
        }

        const float sc = ga.scale;
#pragma unroll
        for (int j = 0; j < 4; ++j) {
            int col = n0 + wn * 64 + j * 16 + ln;
            float bv = ga.bias[col];
#pragma unroll
            for (int i = 0; i < 2; ++i) {
                int row0 = m0 + wm * 32 + i * 16 + lq * 4;
#pragma unroll
                for (int r = 0; r < 4; ++r) {
                    float v = (acc[i][j][r] + bv) * sc;
                    ((unsigned short*)ga.out)[(size_t)(row0 + r) * N + col] = f2b(v);
                }
            }
        }
    } else {
        // -------- k_down path --------
        unsigned short* QD = (unsigned short*)SM;              // 32*72*2  = 4608
        unsigned short* KT = (unsigned short*)(SM + 4608);     // 128*72*2 = 18432
        float* SS          = (float*)(SM + 23040);             // 32*132*4 = 16896
        float* cmf         = (float*)(SM + 39936);             // 128

        const int id = blockIdx.y * 8 + blockIdx.x;            // 0..255
        const unsigned short* qdw = isbf ? qd1 : qd0;
        const int bh = id >> 3;
        const int b = bh >> 4, h = bh & 15;
        const int chunk = id & 7;
        const int s0 = chunk * TSD;

        {
            int r = t >> 3, cb = (t & 7) * 8;   // 256 threads cover 32x64
            *(short8*)&QD[r * 72 + cb] = *(const short8*)&qdw[(size_t)r * DM + h * DH + cb];
        }
        for (int u = t; u < 128 * 8; u += 256) {
            int r = u >> 3, cb = (u & 7) * 8;
            *(short8*)&KT[r * 72 + cb] =
                *(const short8*)&kd[(size_t)((s0 + r) * BATCH + b) * DM + h * DH + cb];
        }
        __syncthreads();

        f32x4 accG[2][2] = {};
#pragma unroll
        for (int ks = 0; ks < 2; ++ks) {
            short8 a8[2], b8[2];
#pragma unroll
            for (int i = 0; i < 2; ++i)
                a8[i] = *(const short8*)&QD[(i * 16 + ln) * 72 + ks * 32 + lq * 8];
#pragma unroll
            for (int j = 0; j < 2; ++j)
                b8[j] = *(const short8*)&KT[(w * 32 + j * 16 + ln) * 72 + ks * 32 + lq * 8];
#pragma unroll
            for (int i = 0; i < 2; ++i)
#pragma unroll
                for (int j = 0; j < 2; ++j)
                    accG[i][j] = __builtin_amdgcn_mfma_f32_16x16x32_bf16(a8[i], b8[j], accG[i][j], 0, 0, 0);
        }
#pragma unroll
        for (int i = 0; i < 2; ++i) {
#pragma unroll
            for (int j = 0; j < 2; ++j) {
                int sl = w * 32 + j * 16 + ln;
#pragma unroll
                for (int r = 0; r < 4; ++r) {
                    int c = i * 16 + lq * 4 + r;
                    float v = accG[i][j][r] * 0.125f;
                    SS[c * 132 + sl] = v;
                    wbuf[((size_t)bh * CC + c) * S_LEN + s0 + sl] = v;
                }
            }
        }
        __syncthreads();

        const int c = t >> 3, sub = t & 7;
        float lmax = -3.4e38f;
#pragma unroll
        for (int k = 0; k < 16; ++k) lmax = fmaxf(lmax, SS[c * 132 + sub * 16 + k]);
        lmax = fmaxf(lmax, __shfl_xor(lmax, 1));
        lmax = fmaxf(lmax, __shfl_xor(lmax, 2));
        lmax = fmaxf(lmax, __shfl_xor(lmax, 4));
        if (sub == 0) {
            cmf[c] = lmax;
            cmax[((size_t)bh * CC + c) * NCHD + chunk] = lmax;
        }
        __syncthreads();
        const float cm = cmf[c];
        float es = 0.f;
#pragma unroll
        for (int k = 0; k < 16; ++k) es += __expf(SS[c * 132 + sub * 16 + k] - cm);
        es += __shfl_xor(es, 1);
        es += __shfl_xor(es, 2);
        es += __shfl_xor(es, 4);
        if (sub == 0) csum[((size_t)bh * CC + c) * NCHD + chunk] = es;
    }
}

// ---------------------------------------------------------------------------
// k_wstate: fused k_wapply + k_state, SPLIT over grid (32 bh, 8 seg, 2 rep)
// = 512 blocks = 2/CU co-resident (45.5 KB LDS), so one block's phase-B
// MFMA hides another's phase-A latency.
//   rep==0: full phase A (writes wb + invn globals, identical arithmetic
//           to the fused version) + state chunk ch = seg*2.
//   rep==1: light phase A (exp(wbuf-gm) -> Wfull LDS only; no global
//           writes, no cumsum) + state chunk ch = seg*2+1.
// ---------------------------------------------------------------------------
__global__ __launch_bounds__(256) void k_wstate(
    const float* __restrict__ wbuf,
    const float* __restrict__ cmax,
    const float* __restrict__ csum,
    const unsigned short* __restrict__ vdk,
    const unsigned short* __restrict__ vdv,
    unsigned short* __restrict__ wb,
    float* __restrict__ invn,
    float* __restrict__ Mst,
    float* __restrict__ NTst)
{
    __shared__ __align__(16) unsigned char SM[45568];
    unsigned short* Wfull = (unsigned short*)SM;             // 32*136*2 = 8704
    unsigned char* R = SM + 8704;                            // 36864-byte reuse region
    // Phase A views
    float* gm    = (float*)R;                                // 128
    float* basep = (float*)(R + 128);                        // 128
    float* psum  = (float*)(R + 256);                        // 32*9*4 = 1152
    float* invt  = (float*)(R + 1408);                       // 128*36*4 = 18432
    // Phase B views
    unsigned short* T1 = (unsigned short*)R;                 // 64*72*2 = 9216
    unsigned short* T2 = (unsigned short*)(R + 9216);        // 9216
    unsigned short* KT = (unsigned short*)(R + 18432);       // 9216
    unsigned short* VT = (unsigned short*)(R + 27648);       // 9216

    const int bh = blockIdx.x, seg = blockIdx.y;
    const int rep = blockIdx.z;
    const int b = bh >> 4, h = bh & 15;
    const int t = threadIdx.x;
    const int w = t >> 6, l = t & 63;
    const int ln = l & 15, lq = l >> 4;

    // ======== Phase A ========
    if (t < CC) {
        const size_t cb = (size_t)(bh * CC + t) * NCHD;
        float m = cmax[cb];
#pragma unroll
        for (int g = 1; g < NCHD; ++g) m = fmaxf(m, cmax[cb + g]);
        gm[t] = m;
        if (rep == 0) {
            float bsum = 0.f;
            for (int k = 0; k < seg; ++k)
                bsum += csum[cb + k] * __expf(cmax[cb + k] - m);
            basep[t] = bsum;
        }
    }
    __syncthreads();

    {
        const int c = t >> 3, sub = t & 7;
        const float gmc = gm[c];
        const size_t rbase = (size_t)bh * 32768 + c * 1024 + seg * 128 + sub * 16;
        float w16[16];
        float s = 0.f;
#pragma unroll
        for (int i = 0; i < 16; ++i) {
            float v = __expf(wbuf[rbase + i] - gmc);
            w16[i] = v; s += v;
        }
        short8 o0, o1;
#pragma unroll
        for (int i = 0; i < 8; ++i) { o0[i] = f2b(w16[i]); o1[i] = f2b(w16[8 + i]); }
        *(short8*)&Wfull[c * 136 + sub * 16] = o0;
        *(short8*)&Wfull[c * 136 + sub * 16 + 8] = o1;
        if (rep == 0) {
            psum[c * 9 + sub] = s;
            *(short8*)&wb[rbase] = o0;
            *(short8*)&wb[rbase + 8] = o1;
            __syncthreads();
            float run = basep[c];
            for (int k = 0; k < sub; ++k) run += psum[c * 9 + k];
#pragma unroll
            for (int i = 0; i < 16; ++i) {
                run += w16[i];
                invt[(sub * 16 + i) * 36 + c] = 1.0f / fmaxf(run, 1e-30f);
            }
        }
    }
    __syncthreads();

    if (rep == 0) {
        for (int u = t; u < 128 * 8; u += 256) {
            int r = u >> 3, cb2 = (u & 7) * 4;
            *(float4*)&invn[(size_t)bh * 32768 + (seg * 128 + r) * 32 + cb2] =
                *(const float4*)&invt[r * 36 + cb2];
        }
    }
    __syncthreads();   // phase-A LDS reads done before T1/T2 reuse

    // ======== Phase B: one state chunk (ch = seg*2 + rep) ========
    {
        const int ch = seg * 2 + rep;
        const int s0 = ch * 64;

        for (int u = t; u < 64 * 8; u += 256) {
            int r = u >> 3, cb = (u & 7) * 8;
            *(short8*)&T1[r * 72 + cb] =
                *(const short8*)&vdk[(size_t)((s0 + r) * BATCH + b) * DM + h * DH + cb];
            *(short8*)&T2[r * 72 + cb] =
                *(const short8*)&vdv[(size_t)((s0 + r) * BATCH + b) * DM + h * DH + cb];
        }
        __syncthreads();
        for (int u = t; u < 64 * 8; u += 256) {
            int d = u >> 3, s8 = (u & 7) * 8;
            short8 o1, o2;
#pragma unroll
            for (int k = 0; k < 8; ++k) {
                o1[k] = T1[(s8 + k) * 72 + d];
                o2[k] = T2[(s8 + k) * 72 + d];
            }
            *(short8*)&KT[d * 72 + s8] = o1;
            *(short8*)&VT[d * 72 + s8] = o2;
        }
        __syncthreads();

        f32x4 accM[2] = {};
#pragma unroll
        for (int ks = 0; ks < 2; ++ks) {
            short8 b8 = *(const short8*)&KT[(w * 16 + ln) * 72 + ks * 32 + lq * 8];
#pragma unroll
            for (int i = 0; i < 2; ++i) {
                short8 a8 = *(const short8*)&Wfull[(i * 16 + ln) * 136 + rep * 64 + ks * 32 + lq * 8];
                accM[i] = __builtin_amdgcn_mfma_f32_16x16x32_bf16(a8, b8, accM[i], 0, 0, 0);
            }
        }
#pragma unroll
        for (int i = 0; i < 2; ++i)
#pragma unroll
            for (int r = 0; r < 4; ++r)
                Mst[((size_t)(bh * 16 + ch) * 32 + i * 16 + lq * 4 + r) * 64 + w * 16 + ln] = accM[i][r];

        f32x4 accN[2] = {};
#pragma unroll
        for (int ks = 0; ks < 2; ++ks) {
            short8 a8 = *(const short8*)&VT[(w * 16 + ln) * 72 + ks * 32 + lq * 8];
#pragma unroll
            for (int j = 0; j < 2; ++j) {
                short8 b8 = *(const short8*)&Wfull[(j * 16 + ln) * 136 + rep * 64 + ks * 32 + lq * 8];
                accN[j] = __builtin_amdgcn_mfma_f32_16x16x32_bf16(a8, b8, accN[j], 0, 0, 0);
            }
        }
#pragma unroll
        for (int j = 0; j < 2; ++j)
#pragma unroll
            for (int r = 0; r < 4; ++r)
                NTst[((size_t)(bh * 16 + ch) * 64 + w * 16 + lq * 4 + r) * 32 + j * 16 + ln] = accN[j][r];
    }
}

// ---------------------------------------------------------------------------
// k_att (chunked): per (bh, q-tile 64). Inline exclusive prefix over
// Mst/NTst chunks 0..qi-1; WTd derived by in-LDS transpose of Wd.
// ---------------------------------------------------------------------------
__global__ __launch_bounds__(256) void k_att(
    const unsigned short* __restrict__ qu,
    const unsigned short* __restrict__ vdk,
    const unsigned short* __restrict__ wb,
    const float* __restrict__ invn,
    const unsigned short* __restrict__ vdv,
    const float* __restrict__ Mst,
    const float* __restrict__ NTst,
    unsigned short* __restrict__ attout)
{
    const int bh = blockIdx.x, b = bh >> 4, h = bh & 15;
    const int qi = blockIdx.y;
    const int s0 = qi * 64;
    const int t = threadIdx.x;
    const int w = t >> 6, l = t & 63;
    const int wy = w >> 1, wx = w & 1;
    const int ln = l & 15, lq = l >> 4;

    __shared__ __align__(16) unsigned short Qs[64 * 72];
    __shared__ __align__(16) unsigned short Gs[64 * 72];
    __shared__ __align__(16) unsigned short Kd[64 * 72];
    __shared__ __align__(16) unsigned short Wd[32 * 72];
    __shared__ __align__(16) unsigned short WTd[64 * 40];
    __shared__ __align__(16) unsigned short VTd[64 * 72];
    __shared__ __align__(16) unsigned short Mc[32 * 72];
    __shared__ __align__(16) unsigned short Nc[64 * 40];

    // P0: stage (vdv rows go into Gs temporarily)
    for (int u = t; u < 64 * 8; u += 256) {
        int r = u >> 3, cb = (u & 7) * 8;
        *(short8*)&Qs[r * 72 + cb] =
            *(const short8*)&qu[(size_t)(s0 + r) * 2048 + b * 1024 + h * 64 + cb];
        *(short8*)&Kd[r * 72 + cb] =
            *(const short8*)&vdk[(size_t)(s0 + r) * 2048 + b * 1024 + h * 64 + cb];
        *(short8*)&Gs[r * 72 + cb] =
            *(const short8*)&vdv[(size_t)(s0 + r) * 2048 + b * 1024 + h * 64 + cb];
    }
    for (int u = t; u < 32 * 8; u += 256) {
        int r = u >> 3, cb = (u & 7) * 8;
        *(short8*)&Wd[r * 72 + cb] =
            *(const short8*)&wb[(size_t)bh * 32768 + r * 1024 + s0 + cb];
    }
    // inline exclusive prefix -> Mc (32x64) and Nc (64x32), bf16
    {
        float am[8] = {0.f, 0.f, 0.f, 0.f, 0.f, 0.f, 0.f, 0.f};
        float an[8] = {0.f, 0.f, 0.f, 0.f, 0.f, 0.f, 0.f, 0.f};
        for (int ch = 0; ch < qi; ++ch) {
            const float* pm = Mst + ((size_t)(bh * 16 + ch)) * 2048 + t * 8;
            const float* pn = NTst + ((size_t)(bh * 16 + ch)) * 2048 + t * 8;
            float4 m0 = *(const float4*)pm;
            float4 m1 = *(const float4*)(pm + 4);
            float4 n0 = *(const float4*)pn;
            float4 n1 = *(const float4*)(pn + 4);
            am[0] += m0.x; am[1] += m0.y; am[2] += m0.z; am[3] += m0.w;
            am[4] += m1.x; am[5] += m1.y; am[6] += m1.z; am[7] += m1.w;
            an[0] += n0.x; an[1] += n0.y; an[2] += n0.z; an[3] += n0.w;
            an[4] += n1.x; an[5] += n1.y; an[6] += n1.z; an[7] += n1.w;
        }
        short8 mo, no;
#pragma unroll
        for (int j = 0; j < 8; ++j) { mo[j] = f2b(am[j]); no[j] = f2b(an[j]); }
        *(short8*)&Mc[(t >> 3) * 72 + (t & 7) * 8] = mo;
        *(short8*)&Nc[(t >> 2) * 40 + (t & 3) * 8] = no;
    }
    __syncthreads();

    // P1: VTd[d][s] = Gs[s][d]; WTd[sl][c] = Wd[c][sl]
    for (int u = t; u < 64 * 8; u += 256) {
        int d = u >> 3, s8 = (u & 7) * 8;
        short8 o;
#pragma unroll
        for (int k = 0; k < 8; ++k) o[k] = Gs[(s8 + k) * 72 + d];
        *(short8*)&VTd[d * 72 + s8] = o;
    }
    {
        int sl = t >> 2, cb = (t & 3) * 8;   // 256 units cover 64x32
        short8 o;
#pragma unroll
        for (int k = 0; k < 8; ++k) o[k] = Wd[(cb + k) * 72 + sl];
        *(short8*)&WTd[sl * 40 + cb] = o;
    }
    __syncthreads();

    // P2: G = q @ k_diag^T, causal, -> Gs
    {
        f32x4 accG[2][2] = {};
#pragma unroll
        for (int ks = 0; ks < 2; ++ks) {
            short8 a8[2], b8[2];
#pragma unroll
            for (int i = 0; i < 2; ++i)
                a8[i] = *(const short8*)&Qs[(wy * 32 + i * 16 + ln) * 72 + ks * 32 + lq * 8];
#pragma unroll
            for (int j = 0; j < 2; ++j)
                b8[j] = *(const short8*)&Kd[(wx * 32 + j * 16 + ln) * 72 + ks * 32 + lq * 8];
#pragma unroll
            for (int i = 0; i < 2; ++i)
#pragma unroll
                for (int j = 0; j < 2; ++j)
                    accG[i][j] = __builtin_amdgcn_mfma_f32_16x16x32_bf16(a8[i], b8[j], accG[i][j], 0, 0, 0);
        }
        __syncthreads();  // VTd transpose reads of Gs done before overwrite
#pragma unroll
        for (int i = 0; i < 2; ++i) {
            int row = wy * 32 + i * 16 + lq * 4;
#pragma unroll
            for (int j = 0; j < 2; ++j) {
                int col = wx * 32 + j * 16 + ln;
#pragma unroll
                for (int r = 0; r < 4; ++r) {
                    float v = accG[i][j][r];
                    if (col > row + r) v = 0.f;
                    Gs[(row + r) * 72 + col] = f2b(v);
                }
            }
        }
    }
    __syncthreads();

    // P3: up = G @ w_diag^T + q @ Mcum^T
    f32x4 accU[2] = {};
#pragma unroll
    for (int ks = 0; ks < 2; ++ks) {
        short8 ga = *(const short8*)&Gs[(w * 16 + ln) * 72 + ks * 32 + lq * 8];
        short8 qa = *(const short8*)&Qs[(w * 16 + ln) * 72 + ks * 32 + lq * 8];
#pragma unroll
        for (int j = 0; j < 2; ++j) {
            short8 wf = *(const short8*)&Wd[(j * 16 + ln) * 72 + ks * 32 + lq * 8];
            short8 mf = *(const short8*)&Mc[(j * 16 + ln) * 72 + ks * 32 + lq * 8];
            accU[j] = __builtin_amdgcn_mfma_f32_16x16x32_bf16(ga, wf, accU[j], 0, 0, 0);
            accU[j] = __builtin_amdgcn_mfma_f32_16x16x32_bf16(qa, mf, accU[j], 0, 0, 0);
        }
    }
    __syncthreads();

    // P4: softmax(up*invn) -> ptil into Qs (stride 40)
    {
        int rowl = w * 16 + lq * 4;
#pragma unroll
        for (int r = 0; r < 4; ++r) {
            int srow = s0 + rowl + r;
            float inv0 = invn[(size_t)bh * 32768 + srow * 32 + ln];
            float inv1 = invn[(size_t)bh * 32768 + srow * 32 + 16 + ln];
            float l0 = accU[0][r] * inv0;
            float l1 = accU[1][r] * inv1;
            float m = fmaxf(l0, l1);
#pragma unroll
            for (int msk = 1; msk < 16; msk <<= 1) m = fmaxf(m, __shfl_xor(m, msk));
            float e0 = __expf(l0 - m), e1 = __expf(l1 - m);
            float Z = e0 + e1;
#pragma unroll
            for (int msk = 1; msk < 16; msk <<= 1) Z += __shfl_xor(Z, msk);
            float iz = 1.0f / Z;
            Qs[(rowl + r) * 40 + ln]      = f2b(e0 * iz * inv0);
            Qs[(rowl + r) * 40 + 16 + ln] = f2b(e1 * iz * inv1);
        }
    }
    __syncthreads();

    // P5: SC = ptil @ wT_diag^T (K=32), causal, -> Gs
    short8 pa[2];
#pragma unroll
    for (int i = 0; i < 2; ++i)
        pa[i] = *(const short8*)&Qs[(wy * 32 + i * 16 + ln) * 40 + lq * 8];
    {
        f32x4 accS[2][2] = {};
        short8 b8[2];
#pragma unroll
        for (int j = 0; j < 2; ++j)
            b8[j] = *(const short8*)&WTd[(wx * 32 + j * 16 + ln) * 40 + lq * 8];
#pragma unroll
        for (int i = 0; i < 2; ++i)
#pragma unroll
            for (int j = 0; j < 2; ++j)
                accS[i][j] = __builtin_amdgcn_mfma_f32_16x16x32_bf16(pa[i], b8[j], accS[i][j], 0, 0, 0);
#pragma unroll
        for (int i = 0; i < 2; ++i) {
            int row = wy * 32 + i * 16 + lq * 4;
#pragma unroll
            for (int j = 0; j < 2; ++j) {
                int col = wx * 32 + j * 16 + ln;
#pragma unroll
                for (int r = 0; r < 4; ++r) {
                    float v = accS[i][j][r];
                    if (col > row + r) v = 0.f;
                    Gs[(row + r) * 72 + col] = f2b(v);
                }
            }
        }
    }
    __syncthreads();

    // P6: out = SC @ vT_diag^T + ptil @ NTcum^T -> attout
    {
        f32x4 accO[2][2] = {};
        short8 n8[2];
#pragma unroll
        for (int j = 0; j < 2; ++j)
            n8[j] = *(const short8*)&Nc[(wx * 32 + j * 16 + ln) * 40 + lq * 8];
#pragma unroll
        for (int i = 0; i < 2; ++i)
#pragma unroll
            for (int j = 0; j < 2; ++j)
                accO[i][j] = __builtin_amdgcn_mfma_f32_16x16x32_bf16(pa[i], n8[j], accO[i][j], 0, 0, 0);
#pragma unroll
        for (int ks = 0; ks < 2; ++ks) {
            short8 a8[2], b8[2];
#pragma unroll
            for (int i = 0; i < 2; ++i)
                a8[i] = *(const short8*)&Gs[(wy * 32 + i * 16 + ln) * 72 + ks * 32 + lq * 8];
#pragma unroll
            for (int j = 0; j < 2; ++j)
                b8[j] = *(const short8*)&VTd[(wx * 32 + j * 16 + ln) * 72 + ks * 32 + lq * 8];
#pragma unroll
            for (int i = 0; i < 2; ++i)
#pragma unroll
                for (int j = 0; j < 2; ++j)
                    accO[i][j] = __builtin_amdgcn_mfma_f32_16x16x32_bf16(a8[i], b8[j], accO[i][j], 0, 0, 0);
        }
#pragma unroll
        for (int i = 0; i < 2; ++i) {
            int rowb = s0 + wy * 32 + i * 16 + lq * 4;
#pragma unroll
            for (int j = 0; j < 2; ++j) {
                int d = wx * 32 + j * 16 + ln;
#pragma unroll
                for (int r = 0; r < 4; ++r)
                    attout[(size_t)(rowb + r) * 2048 + b * 1024 + h * 64 + d] = f2b(accO[i][j][r]);
            }
        }
    }
}

// ---------------------------------------------------------------------------
extern "C" void kernel_launch(void* const* d_in, const int* in_sizes, int n_in,
                              void* d_out, int out_size, void* d_ws, size_t ws_size,
                              hipStream_t stream)
{
    (void)in_sizes; (void)n_in; (void)out_size; (void)ws_size;
    char* ws = (char*)d_ws;
    const size_t MB = (size_t)1 << 20;
    const size_t KB = (size_t)1 << 10;
    unsigned short* attout = (unsigned short*)(ws + 0 * MB);   // 4 MB
    unsigned short* q_u    = (unsigned short*)(ws + 4 * MB);   // 4 MB (pre-scaled)
    unsigned short* k_d    = (unsigned short*)(ws + 8 * MB);   // 4 MB
    unsigned short* v_dk   = (unsigned short*)(ws + 12 * MB);  // 4 MB
    unsigned short* v_dv   = (unsigned short*)(ws + 16 * MB);  // 4 MB
    float* wbuf = (float*)(ws + 20 * MB);                      // 4 MB (down scores)
    unsigned short* wb  = (unsigned short*)(ws + 24 * MB);     // 2 MB [bh][c][s]
    float* invn = (float*)(ws + 28 * MB);                      // 4 MB [bh][s][c]
    float* Mst  = (float*)(ws + 32 * MB);                      // 4 MB
    float* NTst = (float*)(ws + 36 * MB);                      // 4 MB
    unsigned short* xb  = (unsigned short*)(ws + 44 * MB);     // 4 MB
    unsigned short* Wqb = (unsigned short*)(ws + 48 * MB);     // 2 MB
    unsigned short* Wkb = (unsigned short*)(ws + 50 * MB);     // 2 MB
    unsigned short* Wvb = (unsigned short*)(ws + 52 * MB);     // 2 MB
    unsigned short* Wob = (unsigned short*)(ws + 54 * MB);     // 2 MB
    unsigned short* v_d = (unsigned short*)(ws + 56 * MB);     // 4 MB (x@Wv^T+bv)
    unsigned short* qdb = (unsigned short*)(ws + 62 * MB);     // 64 KB
    float* biasf  = (float*)(ws + 62 * MB + 64 * KB);          // 20 KB [bq,bk,bv,bo,zero]
    float* cmax   = (float*)(ws + 62 * MB + 192 * KB);         // 32 KB
    float* csum   = (float*)(ws + 62 * MB + 256 * KB);         // 32 KB
    int*   flag   = (int*)  (ws + 62 * MB + 320 * KB);

    const unsigned short* xraw  = (const unsigned short*)d_in[0];
    const unsigned short* qdraw = (const unsigned short*)d_in[1];
    const unsigned short* wqraw = (const unsigned short*)d_in[2];
    const unsigned short* wkraw = (const unsigned short*)d_in[4];
    const unsigned short* wvraw = (const unsigned short*)d_in[6];
    const unsigned short* woraw = (const unsigned short*)d_in[8];

    // convert (inline sniff; bf16 case converts only biases; Wo deferred)
    k_convert<<<1024, 256, 0, stream>>>(
        d_in[0], d_in[1], d_in[2], d_in[4], d_in[6],
        d_in[3], d_in[5], d_in[7], d_in[9],
        flag, xb, qdb, Wqb, Wkb, Wvb, biasf);

    const float* bqf = biasf;
    const float* bkf = biasf + 1024;
    const float* bvf = biasf + 2048;
    const float* bof = biasf + 3072;

    // projections stage 1 (z=0..2, 64x128 tiles, 256 blocks each)
    // + deferred Wo conversion (z=3). 1024 blocks = 4/CU even.
    GArg gq { xb, xraw, Wqb, wqraw, bqf, (void*)q_u, 0.125f, 1 };
    GArg gk { xb, xraw, Wkb, wkraw, bkf, (void*)k_d, 1.0f, 1 };
    GArg gv { xb, xraw, Wvb, wvraw, bvf, (void*)v_d, 1.0f, 1 };
    k_g1conv<<<dim3(8, 32, 4), 256, 0, stream>>>(gq, gk, gv, flag, SB, DM, DM,
                                                 d_in[8], Wob);

    // fused: stage-2 GEMMs (v_dk, v_dv; z=0,1; 64x128 tiles) + k_down (z=2).
    // 768 blocks = 3/CU even.
    GArg gvk{ v_d, v_d, Wkb, wkraw, bkf, (void*)v_dk, 1.0f, 1 };
    GArg gvv{ v_d, v_d, Wvb, wvraw, bvf, (void*)v_dv, 1.0f, 1 };
    k_g2down<<<dim3(8, 32, 3), 256, 0, stream>>>(gvk, gvv, flag, SB, DM, DM,
                                                 k_d, qdb, qdraw, wbuf, cmax, csum);

    // fused wapply+state, split 512 blocks = 2/CU; then att (512 blocks)
    k_wstate<<<dim3(32, 8, 2), 256, 0, stream>>>(wbuf, cmax, csum, v_dk, v_dv,
                                                 wb, invn, Mst, NTst);
    k_att<<<dim3(32, 16), 256, 0, stream>>>(q_u, v_dk, wb, invn, v_dv,
                                            Mst, NTst, attout);

    // final projection: 64x64 tiles, 512 blocks = 2/CU
    GArg go{ attout, attout, Wob, woraw, bof, d_out, 1.0f, 2 };
    gemm_f64<<<dim3(16, 32), 256, 0, stream>>>(go, flag, SB, DM, DM);
}

// Round 10
// 159.653 us; speedup vs baseline: 1.2238x; 1.0290x over previous
//
#include <hip/hip_runtime.h>
#include <cstdint>
#include <cstddef>

// Problem constants
#define S_LEN 1024
#define BATCH 2
#define DM    1024
#define NH    16
#define DH    64
#define CC    32     // compressed length
#define SB    2048   // S*B rows
#define TSD   128
#define NCHD  8

using short8 = __attribute__((ext_vector_type(8))) short;
using f32x4  = __attribute__((ext_vector_type(4))) float;

__device__ __forceinline__ float b2f(unsigned short u) {
    union { unsigned int i; float f; } v; v.i = ((unsigned int)u) << 16; return v.f;
}
__device__ __forceinline__ unsigned short f2b(float f) {
    union { float f; unsigned int i; } v; v.f = f;
    unsigned int x = v.i;
    unsigned int r = x + 0x7FFFu + ((x >> 16) & 1u);
    return (unsigned short)(r >> 16);
}

__device__ __forceinline__ void async_ld16(const unsigned short* g, unsigned short* l) {
    __builtin_amdgcn_global_load_lds(
        (const __attribute__((address_space(1))) unsigned int*)g,
        (__attribute__((address_space(3))) unsigned int*)l,
        16, 0, 0);
}

// ---------------------------------------------------------------------------
// k_convert: inline dtype sniff. If inputs are bf16, ONLY biases are
// converted (consumers use raw d_in pointers). If fp32, full conversion.
// Wo conversion is deferred to the stage-1 launch (k_g1conv z==3).
// ---------------------------------------------------------------------------
__global__ __launch_bounds__(256) void k_convert(
    const void* x, const void* qd,
    const void* wq, const void* wk, const void* wv,
    const void* bq, const void* bk, const void* bv, const void* bo,
    int* __restrict__ flag,
    unsigned short* xb, unsigned short* qdb,
    unsigned short* Wqb, unsigned short* Wkb, unsigned short* Wvb,
    float* biasf)
{
    __shared__ int cnt;
    if (threadIdx.x == 0) cnt = 0;
    __syncthreads();
    {
        const unsigned short* xs = (const unsigned short*)x;
        int local = 0;
        for (int i = threadIdx.x; i < 1024; i += 256) {
            unsigned e = (xs[i * 2] >> 7) & 0xFF;
            if (e >= 90 && e <= 160) local++;
        }
        atomicAdd(&cnt, local);
    }
    __syncthreads();
    const int isbf = (cnt >= 640);
    if (blockIdx.x == 0 && threadIdx.x == 0) *flag = isbf;

    const size_t tid = (size_t)blockIdx.x * 256 + threadIdx.x;
    const size_t stride = (size_t)gridDim.x * 256;

    if (!isbf) {
        auto cv = [&](const void* src, unsigned short* dst, size_t n) {
            const float4* s = (const float4*)src;
            for (size_t i = tid; i < n / 4; i += stride) {
                float4 v = s[i];
                ushort4 o;
                o.x = f2b(v.x); o.y = f2b(v.y); o.z = f2b(v.z); o.w = f2b(v.w);
                ((ushort4*)dst)[i] = o;
            }
        };
        cv(x,  xb,  (size_t)SB * DM);
        cv(qd, qdb, (size_t)CC * DM);
        cv(wq, Wqb, (size_t)DM * DM);
        cv(wk, Wkb, (size_t)DM * DM);
        cv(wv, Wvb, (size_t)DM * DM);
    }
    for (size_t i = tid; i < 5 * DM; i += stride) {
        int w = (int)(i >> 10), o = (int)(i & 1023);
        float val;
        if (w == 4) val = 0.f;
        else {
            const void* bp = (w == 0) ? bq : ((w == 1) ? bk : ((w == 2) ? bv : bo));
            val = isbf ? b2f(((const unsigned short*)bp)[o]) : ((const float*)bp)[o];
        }
        biasf[i] = val;
    }
}

// ---------------------------------------------------------------------------
// GEMM args. 64-wide-M tile kernels.
// ---------------------------------------------------------------------------
struct GArg {
    const unsigned short* A0;
    const unsigned short* A1;
    const unsigned short* B0;
    const unsigned short* B1;
    const float* bias;
    void* out;
    float scale;
    int mode;
};

// ---------------------------------------------------------------------------
// k_g1conv: stage-1 projections (z=0,1,2: q_u, k_d, v_d; 64x128 tiles,
// BK=64, grid 8x32 per slice = 256 blocks) + deferred Wo conversion (z=3).
// Kept at BK=64: BK=128 would drop 4->3 blocks/CU here (ragged tail).
// ---------------------------------------------------------------------------
__global__ __launch_bounds__(256) void k_g1conv(
    GArg g0, GArg g1, GArg g2, const int* __restrict__ flag,
    int M, int N, int K,
    const void* __restrict__ wo_raw, unsigned short* __restrict__ Wob)
{
    const int isbf = *flag;
    const int t = threadIdx.x;

    if (blockIdx.z == 3) {
        if (!isbf) {
            const float4* s = (const float4*)wo_raw;
            const int id = blockIdx.y * 8 + blockIdx.x;   // 0..255
            for (int i = id * 256 + t; i < (DM * DM) / 4; i += 256 * 256) {
                float4 v = s[i];
                ushort4 o;
                o.x = f2b(v.x); o.y = f2b(v.y); o.z = f2b(v.z); o.w = f2b(v.w);
                ((ushort4*)Wob)[i] = o;
            }
        }
        return;
    }

    GArg ga = (blockIdx.z == 0) ? g0 : (blockIdx.z == 1) ? g1 : g2;
    const unsigned short* Ap = isbf ? ga.A1 : ga.A0;
    const unsigned short* Bp = isbf ? ga.B1 : ga.B0;
    const int m0 = blockIdx.y * 64;
    const int n0 = blockIdx.x * 128;
    __shared__ __align__(16) unsigned short As[2][64 * 32];
    __shared__ __align__(16) unsigned short Bs[2][128 * 32];
    const int w = t >> 6, l = t & 63;
    const int wm = w >> 1, wn = w & 1;
    const int lr = l >> 2;
    const int lk = (l & 3) * 8;
    const int ln = l & 15;
    const int lq = l >> 4;

    f32x4 acc[2][4] = {};

    const unsigned short* Ab  = Ap + (size_t)(m0 + w * 16 +      lr) * K + lk;
    const unsigned short* Bb0 = Bp + (size_t)(n0 + w * 32 +      lr) * K + lk;
    const unsigned short* Bb1 = Bp + (size_t)(n0 + w * 32 + 16 + lr) * K + lk;

    for (int kk = 0; kk < K; kk += 64) {
#pragma unroll
        for (int hh = 0; hh < 2; ++hh) {
            async_ld16(Ab  + kk + hh * 32, &As[hh][w * 512]);
            async_ld16(Bb0 + kk + hh * 32, &Bs[hh][w * 1024]);
            async_ld16(Bb1 + kk + hh * 32, &Bs[hh][w * 1024 + 512]);
        }
        __syncthreads();
#pragma unroll
        for (int hh = 0; hh < 2; ++hh) {
            short8 af[2], bfr[4];
#pragma unroll
            for (int i = 0; i < 2; ++i)
                af[i] = *(const short8*)&As[hh][(wm * 32 + i * 16 + ln) * 32 + lq * 8];
#pragma unroll
            for (int j = 0; j < 4; ++j)
                bfr[j] = *(const short8*)&Bs[hh][(wn * 64 + j * 16 + ln) * 32 + lq * 8];
#pragma unroll
            for (int i = 0; i < 2; ++i)
#pragma unroll
                for (int j = 0; j < 4; ++j)
                    acc[i][j] = __builtin_amdgcn_mfma_f32_16x16x32_bf16(af[i], bfr[j], acc[i][j], 0, 0, 0);
        }
        __syncthreads();
    }

    const float sc = ga.scale;
#pragma unroll
    for (int j = 0; j < 4; ++j) {
        int col = n0 + wn * 64 + j * 16 + ln;
        float bv = ga.bias[col];
#pragma unroll
        for (int i = 0; i < 2; ++i) {
            int row0 = m0 + wm * 32 + i * 16 + lq * 4;
#pragma unroll
            for (int r = 0; r < 4; ++r) {
                float v = (acc[i][j][r] + bv) * sc;
                ((unsigned short*)ga.out)[(size_t)(row0 + r) * N + col] = f2b(v);
            }
        }
    }
}

// ---------------------------------------------------------------------------
// gemm_f64: final projection, 64x64 tiles, BK=128 (8 K-iters -> half the
// barrier drains vs BK=64; LDS 32 KB, grid (16,32)=512 blocks=2/CU same
// occupancy). hh order preserves exact K-accumulation sequence.
// ---------------------------------------------------------------------------
__global__ __launch_bounds__(256) void gemm_f64(GArg ga,
                                                const int* __restrict__ flag,
                                                int M, int N, int K)
{
    const int isbf = *flag;
    const unsigned short* Ap = isbf ? ga.A1 : ga.A0;
    const unsigned short* Bp = isbf ? ga.B1 : ga.B0;
    const int m0 = blockIdx.y * 64;
    const int n0 = blockIdx.x * 64;
    __shared__ __align__(16) unsigned short As[4][64 * 32];
    __shared__ __align__(16) unsigned short Bs[4][64 * 32];
    const int t = threadIdx.x;
    const int w = t >> 6, l = t & 63;
    const int wm = w >> 1, wn = w & 1;
    const int lr = l >> 2;
    const int lk = (l & 3) * 8;
    const int ln = l & 15;
    const int lq = l >> 4;

    f32x4 acc[2][2] = {};

    const unsigned short* Ab = Ap + (size_t)(m0 + w * 16 + lr) * K + lk;
    const unsigned short* Bb = Bp + (size_t)(n0 + w * 16 + lr) * K + lk;

    for (int kk = 0; kk < K; kk += 128) {
#pragma unroll
        for (int hh = 0; hh < 4; ++hh) {
            async_ld16(Ab + kk + hh * 32, &As[hh][w * 512]);
            async_ld16(Bb + kk + hh * 32, &Bs[hh][w * 512]);
        }
        __syncthreads();
#pragma unroll
        for (int hh = 0; hh < 4; ++hh) {
            short8 af[2], bfr[2];
#pragma unroll
            for (int i = 0; i < 2; ++i)
                af[i] = *(const short8*)&As[hh][(wm * 32 + i * 16 + ln) * 32 + lq * 8];
#pragma unroll
            for (int j = 0; j < 2; ++j)
                bfr[j] = *(const short8*)&Bs[hh][(wn * 32 + j * 16 + ln) * 32 + lq * 8];
#pragma unroll
            for (int i = 0; i < 2; ++i)
#pragma unroll
                for (int j = 0; j < 2; ++j)
                    acc[i][j] = __builtin_amdgcn_mfma_f32_16x16x32_bf16(af[i], bfr[j], acc[i][j], 0, 0, 0);
        }
        __syncthreads();
    }

    const int f32o = (ga.mode == 0) ? 1 : (ga.mode == 1) ? 0 : (!isbf);
    const float sc = ga.scale;
#pragma unroll
    for (int j = 0; j < 2; ++j) {
        int col = n0 + wn * 32 + j * 16 + ln;
        float bv = ga.bias[col];
#pragma unroll
        for (int i = 0; i < 2; ++i) {
            int row0 = m0 + wm * 32 + i * 16 + lq * 4;
#pragma unroll
            for (int r = 0; r < 4; ++r) {
                float v = (acc[i][j][r] + bv) * sc;
                size_t idx = (size_t)(row0 + r) * N + col;
                if (f32o) ((float*)ga.out)[idx] = v;
                else      ((unsigned short*)ga.out)[idx] = f2b(v);
            }
        }
    }
}

// ---------------------------------------------------------------------------
// k_g2down: z-fused launch, grid (8, 32, 3). z in {0,1}: stage-2 GEMMs
// (v_dk, v_dv) as 64x128 tiles, BK=128 (8 K-iters, half the barriers;
// LDS 48 KB union -> still 3 blocks/CU: 3x49152 <= 160 KiB).
// z==2: the 256 k_down blocks (id = by*8+bx).
// ---------------------------------------------------------------------------
__global__ __launch_bounds__(256) void k_g2down(
    GArg g0, GArg g1, const int* __restrict__ flag, int M, int N, int K,
    const unsigned short* __restrict__ kd,
    const unsigned short* __restrict__ qd0,
    const unsigned short* __restrict__ qd1,
    float* __restrict__ wbuf,
    float* __restrict__ cmax,
    float* __restrict__ csum)
{
    __shared__ __align__(16) unsigned char SM[49152];
    const int isbf = *flag;
    const int t = threadIdx.x;
    const int w = t >> 6, l = t & 63;
    const int ln = l & 15, lq = l >> 4;

    if (blockIdx.z < 2) {
        // -------- stage-2 GEMM path (64x128 tile, BK=128) --------
        unsigned short* As = (unsigned short*)SM;              // 4 x 64*32  = 16384 B
        unsigned short* Bs = (unsigned short*)(SM + 16384);    // 4 x 128*32 = 32768 B
        GArg ga = blockIdx.z ? g1 : g0;
        const unsigned short* Ap = isbf ? ga.A1 : ga.A0;
        const unsigned short* Bp = isbf ? ga.B1 : ga.B0;
        const int m0 = blockIdx.y * 64;
        const int n0 = blockIdx.x * 128;
        const int wm = w >> 1, wn = w & 1;
        const int lr = l >> 2;
        const int lk = (l & 3) * 8;

        f32x4 acc[2][4] = {};

        const unsigned short* Ab  = Ap + (size_t)(m0 + w * 16 +      lr) * K + lk;
        const unsigned short* Bb0 = Bp + (size_t)(n0 + w * 32 +      lr) * K + lk;
        const unsigned short* Bb1 = Bp + (size_t)(n0 + w * 32 + 16 + lr) * K + lk;

        for (int kk = 0; kk < K; kk += 128) {
#pragma unroll
            for (int hh = 0; hh < 4; ++hh) {
                async_ld16(Ab  + kk + hh * 32, &As[hh * 2048 + w * 512]);
                async_ld16(Bb0 + kk + hh * 32, &Bs[hh * 4096 + w * 1024]);
                async_ld16(Bb1 + kk + hh * 32, &Bs[hh * 4096 + w * 1024 + 512]);
            }
            __syncthreads();
#pragma unroll
            for (int hh = 0; hh < 4; ++hh) {
                short8 af[2], bfr[4];
#pragma unroll
                for (int i = 0; i < 2; ++i)
                    af[i] = *(const short8*)&As[hh * 2048 + (wm * 32 + i * 16 + ln) * 32 + lq * 8];
#pragma unroll
                for (int j = 0; j < 4; ++j)
                    bfr[j] = *(const short8*)&Bs[hh * 4096 + (wn * 64 + j * 16 + ln) * 32 + lq * 8];
#pragma unroll
                for (int i = 0; i < 2; ++i)
#pragma unroll
                    for (int j = 0; j < 4; ++j)
                        acc[i][j] = __builtin_amdgcn_mfma_f32_16x16x32_bf16(af[i], bfr[j], acc[i][j], 0, 0, 0);
            }
            __syncthreads();
        }

        const float sc = ga.scale;
#pragma unroll
        for (int j = 0; j < 4; ++j) {
            int col = n0 + wn * 64 + j * 16 + ln;
            float bv = ga.bias[col];
#pragma unroll
            for (int i = 0; i < 2; ++i) {
                int row0 = m0 + wm * 32 + i * 16 + lq * 4;
#pragma unroll
                for (int r = 0; r < 4; ++r) {
                    float v = (acc[i][j][r] + bv) * sc;
                    ((unsigned short*)ga.out)[(size_t)(row0 + r) * N + col] = f2b(v);
                }
            }
        }
    } else {
        // -------- k_down path --------
        unsigned short* QD = (unsigned short*)SM;              // 32*72*2  = 4608
        unsigned short* KT = (unsigned short*)(SM + 4608);     // 128*72*2 = 18432
        float* SS          = (float*)(SM + 23040);             // 32*132*4 = 16896
        float* cmf         = (float*)(SM + 39936);             // 128

        const int id = blockIdx.y * 8 + blockIdx.x;            // 0..255
        const unsigned short* qdw = isbf ? qd1 : qd0;
        const int bh = id >> 3;
        const int b = bh >> 4, h = bh & 15;
        const int chunk = id & 7;
        const int s0 = chunk * TSD;

        {
            int r = t >> 3, cb = (t & 7) * 8;   // 256 threads cover 32x64
            *(short8*)&QD[r * 72 + cb] = *(const short8*)&qdw[(size_t)r * DM + h * DH + cb];
        }
        for (int u = t; u < 128 * 8; u += 256) {
            int r = u >> 3, cb = (u & 7) * 8;
            *(short8*)&KT[r * 72 + cb] =
                *(const short8*)&kd[(size_t)((s0 + r) * BATCH + b) * DM + h * DH + cb];
        }
        __syncthreads();

        f32x4 accG[2][2] = {};
#pragma unroll
        for (int ks = 0; ks < 2; ++ks) {
            short8 a8[2], b8[2];
#pragma unroll
            for (int i = 0; i < 2; ++i)
                a8[i] = *(const short8*)&QD[(i * 16 + ln) * 72 + ks * 32 + lq * 8];
#pragma unroll
            for (int j = 0; j < 2; ++j)
                b8[j] = *(const short8*)&KT[(w * 32 + j * 16 + ln) * 72 + ks * 32 + lq * 8];
#pragma unroll
            for (int i = 0; i < 2; ++i)
#pragma unroll
                for (int j = 0; j < 2; ++j)
                    accG[i][j] = __builtin_amdgcn_mfma_f32_16x16x32_bf16(a8[i], b8[j], accG[i][j], 0, 0, 0);
        }
#pragma unroll
        for (int i = 0; i < 2; ++i) {
#pragma unroll
            for (int j = 0; j < 2; ++j) {
                int sl = w * 32 + j * 16 + ln;
#pragma unroll
                for (int r = 0; r < 4; ++r) {
                    int c = i * 16 + lq * 4 + r;
                    float v = accG[i][j][r] * 0.125f;
                    SS[c * 132 + sl] = v;
                    wbuf[((size_t)bh * CC + c) * S_LEN + s0 + sl] = v;
                }
            }
        }
        __syncthreads();

        const int c = t >> 3, sub = t & 7;
        float lmax = -3.4e38f;
#pragma unroll
        for (int k = 0; k < 16; ++k) lmax = fmaxf(lmax, SS[c * 132 + sub * 16 + k]);
        lmax = fmaxf(lmax, __shfl_xor(lmax, 1));
        lmax = fmaxf(lmax, __shfl_xor(lmax, 2));
        lmax = fmaxf(lmax, __shfl_xor(lmax, 4));
        if (sub == 0) {
            cmf[c] = lmax;
            cmax[((size_t)bh * CC + c) * NCHD + chunk] = lmax;
        }
        __syncthreads();
        const float cm = cmf[c];
        float es = 0.f;
#pragma unroll
        for (int k = 0; k < 16; ++k) es += __expf(SS[c * 132 + sub * 16 + k] - cm);
        es += __shfl_xor(es, 1);
        es += __shfl_xor(es, 2);
        es += __shfl_xor(es, 4);
        if (sub == 0) csum[((size_t)bh * CC + c) * NCHD + chunk] = es;
    }
}

// ---------------------------------------------------------------------------
// k_wstate: fused k_wapply + k_state, split over grid (32 bh, 8 seg, 2 rep).
//   rep==0: full phase A (writes wb + invn) + state chunk seg*2.
//   rep==1: light phase A (exp -> Wfull only) + state chunk seg*2+1.
// ---------------------------------------------------------------------------
__global__ __launch_bounds__(256) void k_wstate(
    const float* __restrict__ wbuf,
    const float* __restrict__ cmax,
    const float* __restrict__ csum,
    const unsigned short* __restrict__ vdk,
    const unsigned short* __restrict__ vdv,
    unsigned short* __restrict__ wb,
    float* __restrict__ invn,
    float* __restrict__ Mst,
    float* __restrict__ NTst)
{
    __shared__ __align__(16) unsigned char SM[45568];
    unsigned short* Wfull = (unsigned short*)SM;             // 32*136*2 = 8704
    unsigned char* R = SM + 8704;                            // 36864-byte reuse region
    // Phase A views
    float* gm    = (float*)R;                                // 128
    float* basep = (float*)(R + 128);                        // 128
    float* psum  = (float*)(R + 256);                        // 32*9*4 = 1152
    float* invt  = (float*)(R + 1408);                       // 128*36*4 = 18432
    // Phase B views
    unsigned short* T1 = (unsigned short*)R;                 // 64*72*2 = 9216
    unsigned short* T2 = (unsigned short*)(R + 9216);        // 9216
    unsigned short* KT = (unsigned short*)(R + 18432);       // 9216
    unsigned short* VT = (unsigned short*)(R + 27648);       // 9216

    const int bh = blockIdx.x, seg = blockIdx.y;
    const int rep = blockIdx.z;
    const int b = bh >> 4, h = bh & 15;
    const int t = threadIdx.x;
    const int w = t >> 6, l = t & 63;
    const int ln = l & 15, lq = l >> 4;

    // ======== Phase A ========
    if (t < CC) {
        const size_t cb = (size_t)(bh * CC + t) * NCHD;
        float m = cmax[cb];
#pragma unroll
        for (int g = 1; g < NCHD; ++g) m = fmaxf(m, cmax[cb + g]);
        gm[t] = m;
        if (rep == 0) {
            float bsum = 0.f;
            for (int k = 0; k < seg; ++k)
                bsum += csum[cb + k] * __expf(cmax[cb + k] - m);
            basep[t] = bsum;
        }
    }
    __syncthreads();

    {
        const int c = t >> 3, sub = t & 7;
        const float gmc = gm[c];
        const size_t rbase = (size_t)bh * 32768 + c * 1024 + seg * 128 + sub * 16;
        float w16[16];
        float s = 0.f;
#pragma unroll
        for (int i = 0; i < 16; ++i) {
            float v = __expf(wbuf[rbase + i] - gmc);
            w16[i] = v; s += v;
        }
        short8 o0, o1;
#pragma unroll
        for (int i = 0; i < 8; ++i) { o0[i] = f2b(w16[i]); o1[i] = f2b(w16[8 + i]); }
        *(short8*)&Wfull[c * 136 + sub * 16] = o0;
        *(short8*)&Wfull[c * 136 + sub * 16 + 8] = o1;
        if (rep == 0) {
            psum[c * 9 + sub] = s;
            *(short8*)&wb[rbase] = o0;
            *(short8*)&wb[rbase + 8] = o1;
            __syncthreads();
            float run = basep[c];
            for (int k = 0; k < sub; ++k) run += psum[c * 9 + k];
#pragma unroll
            for (int i = 0; i < 16; ++i) {
                run += w16[i];
                invt[(sub * 16 + i) * 36 + c] = 1.0f / fmaxf(run, 1e-30f);
            }
        }
    }
    __syncthreads();

    if (rep == 0) {
        for (int u = t; u < 128 * 8; u += 256) {
            int r = u >> 3, cb2 = (u & 7) * 4;
            *(float4*)&invn[(size_t)bh * 32768 + (seg * 128 + r) * 32 + cb2] =
                *(const float4*)&invt[r * 36 + cb2];
        }
    }
    __syncthreads();   // phase-A LDS reads done before T1/T2 reuse

    // ======== Phase B: one state chunk (ch = seg*2 + rep) ========
    {
        const int ch = seg * 2 + rep;
        const int s0 = ch * 64;

        for (int u = t; u < 64 * 8; u += 256) {
            int r = u >> 3, cb = (u & 7) * 8;
            *(short8*)&T1[r * 72 + cb] =
                *(const short8*)&vdk[(size_t)((s0 + r) * BATCH + b) * DM + h * DH + cb];
            *(short8*)&T2[r * 72 + cb] =
                *(const short8*)&vdv[(size_t)((s0 + r) * BATCH + b) * DM + h * DH + cb];
        }
        __syncthreads();
        for (int u = t; u < 64 * 8; u += 256) {
            int d = u >> 3, s8 = (u & 7) * 8;
            short8 o1, o2;
#pragma unroll
            for (int k = 0; k < 8; ++k) {
                o1[k] = T1[(s8 + k) * 72 + d];
                o2[k] = T2[(s8 + k) * 72 + d];
            }
            *(short8*)&KT[d * 72 + s8] = o1;
            *(short8*)&VT[d * 72 + s8] = o2;
        }
        __syncthreads();

        f32x4 accM[2] = {};
#pragma unroll
        for (int ks = 0; ks < 2; ++ks) {
            short8 b8 = *(const short8*)&KT[(w * 16 + ln) * 72 + ks * 32 + lq * 8];
#pragma unroll
            for (int i = 0; i < 2; ++i) {
                short8 a8 = *(const short8*)&Wfull[(i * 16 + ln) * 136 + rep * 64 + ks * 32 + lq * 8];
                accM[i] = __builtin_amdgcn_mfma_f32_16x16x32_bf16(a8, b8, accM[i], 0, 0, 0);
            }
        }
#pragma unroll
        for (int i = 0; i < 2; ++i)
#pragma unroll
            for (int r = 0; r < 4; ++r)
                Mst[((size_t)(bh * 16 + ch) * 32 + i * 16 + lq * 4 + r) * 64 + w * 16 + ln] = accM[i][r];

        f32x4 accN[2] = {};
#pragma unroll
        for (int ks = 0; ks < 2; ++ks) {
            short8 a8 = *(const short8*)&VT[(w * 16 + ln) * 72 + ks * 32 + lq * 8];
#pragma unroll
            for (int j = 0; j < 2; ++j) {
                short8 b8 = *(const short8*)&Wfull[(j * 16 + ln) * 136 + rep * 64 + ks * 32 + lq * 8];
                accN[j] = __builtin_amdgcn_mfma_f32_16x16x32_bf16(a8, b8, accN[j], 0, 0, 0);
            }
        }
#pragma unroll
        for (int j = 0; j < 2; ++j)
#pragma unroll
            for (int r = 0; r < 4; ++r)
                NTst[((size_t)(bh * 16 + ch) * 64 + w * 16 + lq * 4 + r) * 32 + j * 16 + ln] = accN[j][r];
    }
}

// ---------------------------------------------------------------------------
// k_att (chunked): per (bh, q-tile 64). Inline exclusive prefix over
// Mst/NTst chunks 0..qi-1; WTd derived by in-LDS transpose of Wd.
// ---------------------------------------------------------------------------
__global__ __launch_bounds__(256) void k_att(
    const unsigned short* __restrict__ qu,
    const unsigned short* __restrict__ vdk,
    const unsigned short* __restrict__ wb,
    const float* __restrict__ invn,
    const unsigned short* __restrict__ vdv,
    const float* __restrict__ Mst,
    const float* __restrict__ NTst,
    unsigned short* __restrict__ attout)
{
    const int bh = blockIdx.x, b = bh >> 4, h = bh & 15;
    const int qi = blockIdx.y;
    const int s0 = qi * 64;
    const int t = threadIdx.x;
    const int w = t >> 6, l = t & 63;
    const int wy = w >> 1, wx = w & 1;
    const int ln = l & 15, lq = l >> 4;

    __shared__ __align__(16) unsigned short Qs[64 * 72];
    __shared__ __align__(16) unsigned short Gs[64 * 72];
    __shared__ __align__(16) unsigned short Kd[64 * 72];
    __shared__ __align__(16) unsigned short Wd[32 * 72];
    __shared__ __align__(16) unsigned short WTd[64 * 40];
    __shared__ __align__(16) unsigned short VTd[64 * 72];
    __shared__ __align__(16) unsigned short Mc[32 * 72];
    __shared__ __align__(16) unsigned short Nc[64 * 40];

    // P0: stage (vdv rows go into Gs temporarily)
    for (int u = t; u < 64 * 8; u += 256) {
        int r = u >> 3, cb = (u & 7) * 8;
        *(short8*)&Qs[r * 72 + cb] =
            *(const short8*)&qu[(size_t)(s0 + r) * 2048 + b * 1024 + h * 64 + cb];
        *(short8*)&Kd[r * 72 + cb] =
            *(const short8*)&vdk[(size_t)(s0 + r) * 2048 + b * 1024 + h * 64 + cb];
        *(short8*)&Gs[r * 72 + cb] =
            *(const short8*)&vdv[(size_t)(s0 + r) * 2048 + b * 1024 + h * 64 + cb];
    }
    for (int u = t; u < 32 * 8; u += 256) {
        int r = u >> 3, cb = (u & 7) * 8;
        *(short8*)&Wd[r * 72 + cb] =
            *(const short8*)&wb[(size_t)bh * 32768 + r * 1024 + s0 + cb];
    }
    // inline exclusive prefix -> Mc (32x64) and Nc (64x32), bf16
    {
        float am[8] = {0.f, 0.f, 0.f, 0.f, 0.f, 0.f, 0.f, 0.f};
        float an[8] = {0.f, 0.f, 0.f, 0.f, 0.f, 0.f, 0.f, 0.f};
        for (int ch = 0; ch < qi; ++ch) {
            const float* pm = Mst + ((size_t)(bh * 16 + ch)) * 2048 + t * 8;
            const float* pn = NTst + ((size_t)(bh * 16 + ch)) * 2048 + t * 8;
            float4 m0 = *(const float4*)pm;
            float4 m1 = *(const float4*)(pm + 4);
            float4 n0 = *(const float4*)pn;
            float4 n1 = *(const float4*)(pn + 4);
            am[0] += m0.x; am[1] += m0.y; am[2] += m0.z; am[3] += m0.w;
            am[4] += m1.x; am[5] += m1.y; am[6] += m1.z; am[7] += m1.w;
            an[0] += n0.x; an[1] += n0.y; an[2] += n0.z; an[3] += n0.w;
            an[4] += n1.x; an[5] += n1.y; an[6] += n1.z; an[7] += n1.w;
        }
        short8 mo, no;
#pragma unroll
        for (int j = 0; j < 8; ++j) { mo[j] = f2b(am[j]); no[j] = f2b(an[j]); }
        *(short8*)&Mc[(t >> 3) * 72 + (t & 7) * 8] = mo;
        *(short8*)&Nc[(t >> 2) * 40 + (t & 3) * 8] = no;
    }
    __syncthreads();

    // P1: VTd[d][s] = Gs[s][d]; WTd[sl][c] = Wd[c][sl]
    for (int u = t; u < 64 * 8; u += 256) {
        int d = u >> 3, s8 = (u & 7) * 8;
        short8 o;
#pragma unroll
        for (int k = 0; k < 8; ++k) o[k] = Gs[(s8 + k) * 72 + d];
        *(short8*)&VTd[d * 72 + s8] = o;
    }
    {
        int sl = t >> 2, cb = (t & 3) * 8;   // 256 units cover 64x32
        short8 o;
#pragma unroll
        for (int k = 0; k < 8; ++k) o[k] = Wd[(cb + k) * 72 + sl];
        *(short8*)&WTd[sl * 40 + cb] = o;
    }
    __syncthreads();

    // P2: G = q @ k_diag^T, causal, -> Gs
    {
        f32x4 accG[2][2] = {};
#pragma unroll
        for (int ks = 0; ks < 2; ++ks) {
            short8 a8[2], b8[2];
#pragma unroll
            for (int i = 0; i < 2; ++i)
                a8[i] = *(const short8*)&Qs[(wy * 32 + i * 16 + ln) * 72 + ks * 32 + lq * 8];
#pragma unroll
            for (int j = 0; j < 2; ++j)
                b8[j] = *(const short8*)&Kd[(wx * 32 + j * 16 + ln) * 72 + ks * 32 + lq * 8];
#pragma unroll
            for (int i = 0; i < 2; ++i)
#pragma unroll
                for (int j = 0; j < 2; ++j)
                    accG[i][j] = __builtin_amdgcn_mfma_f32_16x16x32_bf16(a8[i], b8[j], accG[i][j], 0, 0, 0);
        }
        __syncthreads();  // VTd transpose reads of Gs done before overwrite
#pragma unroll
        for (int i = 0; i < 2; ++i) {
            int row = wy * 32 + i * 16 + lq * 4;
#pragma unroll
            for (int j = 0; j < 2; ++j) {
                int col = wx * 32 + j * 16 + ln;
#pragma unroll
                for (int r = 0; r < 4; ++r) {
                    float v = accG[i][j][r];
                    if (col > row + r) v = 0.f;
                    Gs[(row + r) * 72 + col] = f2b(v);
                }
            }
        }
    }
    __syncthreads();

    // P3: up = G @ w_diag^T + q @ Mcum^T
    f32x4 accU[2] = {};
#pragma unroll
    for (int ks = 0; ks < 2; ++ks) {
        short8 ga = *(const short8*)&Gs[(w * 16 + ln) * 72 + ks * 32 + lq * 8];
        short8 qa = *(const short8*)&Qs[(w * 16 + ln) * 72 + ks * 32 + lq * 8];
#pragma unroll
        for (int j = 0; j < 2; ++j) {
            short8 wf = *(const short8*)&Wd[(j * 16 + ln) * 72 + ks * 32 + lq * 8];
            short8 mf = *(const short8*)&Mc[(j * 16 + ln) * 72 + ks * 32 + lq * 8];
            accU[j] = __builtin_amdgcn_mfma_f32_16x16x32_bf16(ga, wf, accU[j], 0, 0, 0);
            accU[j] = __builtin_amdgcn_mfma_f32_16x16x32_bf16(qa, mf, accU[j], 0, 0, 0);
        }
    }
    __syncthreads();

    // P4: softmax(up*invn) -> ptil into Qs (stride 40)
    {
        int rowl = w * 16 + lq * 4;
#pragma unroll
        for (int r = 0; r < 4; ++r) {
            int srow = s0 + rowl + r;
            float inv0 = invn[(size_t)bh * 32768 + srow * 32 + ln];
            float inv1 = invn[(size_t)bh * 32768 + srow * 32 + 16 + ln];
            float l0 = accU[0][r] * inv0;
            float l1 = accU[1][r] * inv1;
            float m = fmaxf(l0, l1);
#pragma unroll
            for (int msk = 1; msk < 16; msk <<= 1) m = fmaxf(m, __shfl_xor(m, msk));
            float e0 = __expf(l0 - m), e1 = __expf(l1 - m);
            float Z = e0 + e1;
#pragma unroll
            for (int msk = 1; msk < 16; msk <<= 1) Z += __shfl_xor(Z, msk);
            float iz = 1.0f / Z;
            Qs[(rowl + r) * 40 + ln]      = f2b(e0 * iz * inv0);
            Qs[(rowl + r) * 40 + 16 + ln] = f2b(e1 * iz * inv1);
        }
    }
    __syncthreads();

    // P5: SC = ptil @ wT_diag^T (K=32), causal, -> Gs
    short8 pa[2];
#pragma unroll
    for (int i = 0; i < 2; ++i)
        pa[i] = *(const short8*)&Qs[(wy * 32 + i * 16 + ln) * 40 + lq * 8];
    {
        f32x4 accS[2][2] = {};
        short8 b8[2];
#pragma unroll
        for (int j = 0; j < 2; ++j)
            b8[j] = *(const short8*)&WTd[(wx * 32 + j * 16 + ln) * 40 + lq * 8];
#pragma unroll
        for (int i = 0; i < 2; ++i)
#pragma unroll
            for (int j = 0; j < 2; ++j)
                accS[i][j] = __builtin_amdgcn_mfma_f32_16x16x32_bf16(pa[i], b8[j], accS[i][j], 0, 0, 0);
#pragma unroll
        for (int i = 0; i < 2; ++i) {
            int row = wy * 32 + i * 16 + lq * 4;
#pragma unroll
            for (int j = 0; j < 2; ++j) {
                int col = wx * 32 + j * 16 + ln;
#pragma unroll
                for (int r = 0; r < 4; ++r) {
                    float v = accS[i][j][r];
                    if (col > row + r) v = 0.f;
                    Gs[(row + r) * 72 + col] = f2b(v);
                }
            }
        }
    }
    __syncthreads();

    // P6: out = SC @ vT_diag^T + ptil @ NTcum^T -> attout
    {
        f32x4 accO[2][2] = {};
        short8 n8[2];
#pragma unroll
        for (int j = 0; j < 2; ++j)
            n8[j] = *(const short8*)&Nc[(wx * 32 + j * 16 + ln) * 40 + lq * 8];
#pragma unroll
        for (int i = 0; i < 2; ++i)
#pragma unroll
            for (int j = 0; j < 2; ++j)
                accO[i][j] = __builtin_amdgcn_mfma_f32_16x16x32_bf16(pa[i], n8[j], accO[i][j], 0, 0, 0);
#pragma unroll
        for (int ks = 0; ks < 2; ++ks) {
            short8 a8[2], b8[2];
#pragma unroll
            for (int i = 0; i < 2; ++i)
                a8[i] = *(const short8*)&Gs[(wy * 32 + i * 16 + ln) * 72 + ks * 32 + lq * 8];
#pragma unroll
            for (int j = 0; j < 2; ++j)
                b8[j] = *(const short8*)&VTd[(wx * 32 + j * 16 + ln) * 72 + ks * 32 + lq * 8];
#pragma unroll
            for (int i = 0; i < 2; ++i)
#pragma unroll
                for (int j = 0; j < 2; ++j)
                    accO[i][j] = __builtin_amdgcn_mfma_f32_16x16x32_bf16(a8[i], b8[j], accO[i][j], 0, 0, 0);
        }
#pragma unroll
        for (int i = 0; i < 2; ++i) {
            int rowb = s0 + wy * 32 + i * 16 + lq * 4;
#pragma unroll
            for (int j = 0; j < 2; ++j) {
                int d = wx * 32 + j * 16 + ln;
#pragma unroll
                for (int r = 0; r < 4; ++r)
                    attout[(size_t)(rowb + r) * 2048 + b * 1024 + h * 64 + d] = f2b(accO[i][j][r]);
            }
        }
    }
}

// ---------------------------------------------------------------------------
extern "C" void kernel_launch(void* const* d_in, const int* in_sizes, int n_in,
                              void* d_out, int out_size, void* d_ws, size_t ws_size,
                              hipStream_t stream)
{
    (void)in_sizes; (void)n_in; (void)out_size; (void)ws_size;
    char* ws = (char*)d_ws;
    const size_t MB = (size_t)1 << 20;
    const size_t KB = (size_t)1 << 10;
    unsigned short* attout = (unsigned short*)(ws + 0 * MB);   // 4 MB
    unsigned short* q_u    = (unsigned short*)(ws + 4 * MB);   // 4 MB (pre-scaled)
    unsigned short* k_d    = (unsigned short*)(ws + 8 * MB);   // 4 MB
    unsigned short* v_dk   = (unsigned short*)(ws + 12 * MB);  // 4 MB
    unsigned short* v_dv   = (unsigned short*)(ws + 16 * MB);  // 4 MB
    float* wbuf = (float*)(ws + 20 * MB);                      // 4 MB (down scores)
    unsigned short* wb  = (unsigned short*)(ws + 24 * MB);     // 2 MB [bh][c][s]
    float* invn = (float*)(ws + 28 * MB);                      // 4 MB [bh][s][c]
    float* Mst  = (float*)(ws + 32 * MB);                      // 4 MB
    float* NTst = (float*)(ws + 36 * MB);                      // 4 MB
    unsigned short* xb  = (unsigned short*)(ws + 44 * MB);     // 4 MB
    unsigned short* Wqb = (unsigned short*)(ws + 48 * MB);     // 2 MB
    unsigned short* Wkb = (unsigned short*)(ws + 50 * MB);     // 2 MB
    unsigned short* Wvb = (unsigned short*)(ws + 52 * MB);     // 2 MB
    unsigned short* Wob = (unsigned short*)(ws + 54 * MB);     // 2 MB
    unsigned short* v_d = (unsigned short*)(ws + 56 * MB);     // 4 MB (x@Wv^T+bv)
    unsigned short* qdb = (unsigned short*)(ws + 62 * MB);     // 64 KB
    float* biasf  = (float*)(ws + 62 * MB + 64 * KB);          // 20 KB [bq,bk,bv,bo,zero]
    float* cmax   = (float*)(ws + 62 * MB + 192 * KB);         // 32 KB
    float* csum   = (float*)(ws + 62 * MB + 256 * KB);         // 32 KB
    int*   flag   = (int*)  (ws + 62 * MB + 320 * KB);

    const unsigned short* xraw  = (const unsigned short*)d_in[0];
    const unsigned short* qdraw = (const unsigned short*)d_in[1];
    const unsigned short* wqraw = (const unsigned short*)d_in[2];
    const unsigned short* wkraw = (const unsigned short*)d_in[4];
    const unsigned short* wvraw = (const unsigned short*)d_in[6];
    const unsigned short* woraw = (const unsigned short*)d_in[8];

    // convert (inline sniff; bf16 case converts only biases; Wo deferred)
    k_convert<<<1024, 256, 0, stream>>>(
        d_in[0], d_in[1], d_in[2], d_in[4], d_in[6],
        d_in[3], d_in[5], d_in[7], d_in[9],
        flag, xb, qdb, Wqb, Wkb, Wvb, biasf);

    const float* bqf = biasf;
    const float* bkf = biasf + 1024;
    const float* bvf = biasf + 2048;
    const float* bof = biasf + 3072;

    // projections stage 1 (z=0..2, 64x128 tiles BK=64, 256 blocks each)
    // + deferred Wo conversion (z=3). 1024 blocks = 4/CU even.
    GArg gq { xb, xraw, Wqb, wqraw, bqf, (void*)q_u, 0.125f, 1 };
    GArg gk { xb, xraw, Wkb, wkraw, bkf, (void*)k_d, 1.0f, 1 };
    GArg gv { xb, xraw, Wvb, wvraw, bvf, (void*)v_d, 1.0f, 1 };
    k_g1conv<<<dim3(8, 32, 4), 256, 0, stream>>>(gq, gk, gv, flag, SB, DM, DM,
                                                 d_in[8], Wob);

    // fused: stage-2 GEMMs (v_dk, v_dv; z=0,1; 64x128 tiles BK=128) +
    // k_down (z=2). 768 blocks = 3/CU even (48 KB LDS union).
    GArg gvk{ v_d, v_d, Wkb, wkraw, bkf, (void*)v_dk, 1.0f, 1 };
    GArg gvv{ v_d, v_d, Wvb, wvraw, bvf, (void*)v_dv, 1.0f, 1 };
    k_g2down<<<dim3(8, 32, 3), 256, 0, stream>>>(gvk, gvv, flag, SB, DM, DM,
                                                 k_d, qdb, qdraw, wbuf, cmax, csum);

    // fused wapply+state, split 512 blocks = 2/CU; then att (512 blocks)
    k_wstate<<<dim3(32, 8, 2), 256, 0, stream>>>(wbuf, cmax, csum, v_dk, v_dv,
                                                 wb, invn, Mst, NTst);
    k_att<<<dim3(32, 16), 256, 0, stream>>>(q_u, v_dk, wb, invn, v_dv,
                                            Mst, NTst, attout);

    // final projection: 64x64 tiles BK=128, 512 blocks = 2/CU
    GArg go{ attout, attout, Wob, woraw, bof, d_out, 1.0f, 2 };
    gemm_f64<<<dim3(16, 32), 256, 0, stream>>>(go, flag, SB, DM, DM);
}